// Round 10
// baseline (8102.927 us; speedup 1.0000x reference)
//
#include <hip/hip_runtime.h>

// Problem constants (fixed by setup_inputs)
#define BB 32
#define NN 64
#define TT 11
#define FF 4
#define KK 2
#define EE 4032      // N*(N-1)
#define NSTEP 10

typedef _Float16 f16x8 __attribute__((ext_vector_type(8)));
typedef float    f32x4v __attribute__((ext_vector_type(4)));

// ---- fused kernel LDS (512 thr, 8 receivers, grid 256 = 1 block/CU) ----
// phase C: u dbuf [2][64][512B XOR-swz] 64K | vbh dbuf [2][8][256]f16 8K |
//          y [64][4]f32 1K | wgt [2][8][64]f32 4K  (wgt persists across all phases)
// phase D aliases the (dead) u region: augH [16][296]f16 9472 | P1H [16][264]f16 8448 |
//          P2 [16][256]f32 16384  (total 34304 < 65536)
#define OFF_U0   0
#define OFF_VB   65536
#define OFF_Y    73728
#define OFF_WGT  74752
#define SMEM2    78848
#define OFF_AUGH 0
#define OFF_P1H  9472
#define OFF_P2   17920

__device__ __forceinline__ float scrub(float v) {
    return fminf(fmaxf(v, -3.0e4f), 3.0e4f);   // inactive when correct (|x| <~ 600)
}

__device__ __forceinline__ float load_dt(const float* ts, const void* scp, int step) {
    float t0 = ts[step], t1 = ts[step + 1];
    int w = ((const int*)scp)[0];
    float scl;
    if (w > 0 && w < 1000000) scl = (float)w;            // int32 (live path)
    else {
        float f = __int_as_float(w);
        scl = (f > 0.5f && f < 1.0e6f) ? f : 10.0f;
    }
    return (t1 - t0) / scl;
}

// Device-scope grid barrier: monotonic counter, goal = phase*gridDim. Safe because
// grid = 256 = 1 block/CU (reg-capped) -> all blocks resident. atomicAdd on global
// is device-scope [m20]; threadfence gives release/acquire around the spin.
__device__ __forceinline__ void gbar(unsigned* cnt, unsigned goal) {
    __syncthreads();
    if (threadIdx.x == 0) {
        __threadfence();                         // release block's global writes
        atomicAdd(cnt, 1u);
        while (atomicAdd(cnt, 0u) < goal)
            __builtin_amdgcn_s_sleep(2);
        __threadfence();                         // acquire others' writes
    }
    __syncthreads();
}

// u-build (512 thr): u[s][h] = sum_f y_s[f] * W1send[k][f][h], f16, XOR-swizzled rows.
__device__ __forceinline__ void build_uk(char* smem, int buf, int k, int tid,
    const float* __restrict__ W1g, const float* smY)
{
    int hg = tid & 31, sb = tid >> 5;          // sb = 0..15
    const float* w1p = W1g + k * 2048 + hg * 8;
    f32x4v wA[4], wB[4];
    #pragma unroll
    for (int f = 0; f < 4; ++f) {
        wA[f] = *(const f32x4v*)(w1p + f * 256);
        wB[f] = *(const f32x4v*)(w1p + f * 256 + 4);
    }
    const int swz = (hg * 16) ^ ((sb & 7) << 4);   // s&7 == sb&7 (it*16 ≡ 0 mod 8)
    char* ub = smem + OFF_U0 + buf * 32768;
    #pragma unroll
    for (int it = 0; it < 4; ++it) {
        int s = sb + it * 16;
        f32x4v yv = *(const f32x4v*)(smY + s * 4);
        f16x8 uv;
        #pragma unroll
        for (int e = 0; e < 4; ++e) {
            float vA = yv[0]*wA[0][e] + yv[1]*wA[1][e] + yv[2]*wA[2][e] + yv[3]*wA[3][e];
            float vB = yv[0]*wB[0][e] + yv[1]*wB[1][e] + yv[2]*wB[2][e] + yv[3]*wB[3][e];
            uv[e]     = (_Float16)vA;
            uv[e + 4] = (_Float16)vB;
        }
        *(f16x8*)(ub + s * 512 + swz) = uv;
    }
}

// vbh[buf][rv][h] = f16( b1 + sum_f y_recv[f] * W1recv[k][f][h] ), rv = 0..7
__device__ __forceinline__ void build_vbh(_Float16* smVBH, int buf, int k, int tid, int r0,
    const float* __restrict__ W1g, const float* __restrict__ b1g, const float* smY)
{
    #pragma unroll
    for (int it = 0; it < 4; ++it) {
        int i = tid + it * 512;
        int rv = i >> 8, h = i & 255;
        float acch = b1g[k * 256 + h];
        #pragma unroll
        for (int f = 0; f < 4; ++f)
            acch += smY[(r0 + rv) * 4 + f] * W1g[k * 2048 + (4 + f) * 256 + h];
        smVBH[buf * 2048 + i] = (_Float16)acch;
    }
}

// One GEMM half-pass: wave owns ONE receiver rv; 64 sender-rows (4 mi) x 128 cols
// (col-half ch2), one k. Per kc: 4 u-reads + 1 vb-read feed 32 MFMAs.
// relu(acc)*w accumulated into rsum[8] registers (across both k).
__device__ __forceinline__ void gemm_half(char* smem, int buf, int k, int rv, int ch2,
    const _Float16* __restrict__ W2F, const float* __restrict__ b2g,
    const float* smWgt,
    int lane, int ln15, int lg, const int* uoff, int xm6,
    float rsum[8])
{
    const _Float16* smVBH = (const _Float16*)(smem + OFF_VB);

    float bv[8];
    #pragma unroll
    for (int ni = 0; ni < 8; ++ni)
        bv[ni] = b2g[k * 256 + ch2 * 128 + ni * 16 + ln15];

    f32x4v acc[4][8];         // b2 folded into init; 128 AGPR
    #pragma unroll
    for (int mi = 0; mi < 4; ++mi)
        #pragma unroll
        for (int ni = 0; ni < 8; ++ni)
            acc[mi][ni] = (f32x4v){bv[ni], bv[ni], bv[ni], bv[ni]};

    const _Float16* bbase = W2F + ((size_t)((k * 16 + ch2 * 8) * 8)) * 512 + lane * 8;
    const char* ubase = smem + OFF_U0 + buf * 32768;
    const _Float16* vbase = smVBH + buf * 2048 + rv * 256;

    #pragma unroll
    for (int kc = 0; kc < 8; ++kc) {
        f16x8 bfr[8];
        #pragma unroll
        for (int ni = 0; ni < 8; ++ni)
            bfr[ni] = *(const f16x8*)(bbase + (size_t)(ni * 8 + kc) * 512);
        f16x8 vbv = *(const f16x8*)(vbase + kc * 32 + lg * 8);
        const int kco = (kc * 64) ^ xm6;
        f16x8 af[4];
        f16x8 z = {};
        #pragma unroll
        for (int mi = 0; mi < 4; ++mi) {
            f16x8 uv = *(const f16x8*)(ubase + uoff[mi] + kco);
            af[mi] = __builtin_elementwise_max(uv + vbv, z);
        }
        __builtin_amdgcn_s_setprio(1);
        #pragma unroll
        for (int mi = 0; mi < 4; ++mi)
            #pragma unroll
            for (int ni = 0; ni < 8; ++ni)
                acc[mi][ni] = __builtin_amdgcn_mfma_f32_16x16x32_f16(
                    af[mi], bfr[ni], acc[mi][ni], 0, 0, 0);
        __builtin_amdgcn_s_setprio(0);
    }

    // ---- epilogue: relu * edge_w into rsum regs ----
    #pragma unroll
    for (int mi = 0; mi < 4; ++mi) {
        #pragma unroll
        for (int rr = 0; rr < 4; ++rr) {
            // C/D: col = lane&15, row = lg*4 + rr  [m89/m91]; sender s = mi*16 + row
            float w = smWgt[k * 512 + rv * 64 + mi * 16 + lg * 4 + rr];
            #pragma unroll
            for (int ni = 0; ni < 8; ++ni)
                rsum[ni] += fmaxf(acc[mi][ni][rr], 0.0f) * w;
        }
    }
}

// v10: whole RK4 solve in ONE kernel. Grid 256 = 1 block/CU (all blocks resident);
// 39 manual grid barriers replace 39 kernel-launch boundaries. Edge weights loaded
// to LDS ONCE (invariant across all 40 phases; wgt region survives phase-D aliasing).
// Phase C/D bodies identical to v9 (best verified), minus the provably-dead mid-L1
// barrier (augH [0,9472) and P1H [9472,17920) are disjoint).
__global__ __launch_bounds__(512, 2)
void ode_kernel(const float* __restrict__ edges, const float* __restrict__ W1g,
    const float* __restrict__ b1g,   const _Float16* __restrict__ W2F,
    const float* __restrict__ b2g,
    const _Float16* __restrict__ Wo1F, const float* __restrict__ bo1,
    const _Float16* __restrict__ Wo2F, const float* __restrict__ bo2,
    const float* __restrict__ Wo3, const float* __restrict__ bo3,
    const float* __restrict__ ts,  const void* __restrict__ scp,
    float* __restrict__ xA, float* __restrict__ xB,
    float* __restrict__ k1, float* __restrict__ k2, float* __restrict__ k3,
    float* __restrict__ outp, unsigned* __restrict__ gcnt)
{
    extern __shared__ char smem[];
    _Float16* smVBH = (_Float16*)(smem + OFF_VB);
    float*  smY   = (float*)(smem + OFF_Y);
    float*  smWgt = (float*)(smem + OFF_WGT);

    const int tid = threadIdx.x;
    const int b   = blockIdx.x >> 3;
    const int rg  = blockIdx.x & 7;
    const int r0  = rg * 8;

    const int lane = tid & 63;
    const int wn   = tid >> 6;    // 8 waves: wave wn owns receiver rv = wn
    const int rv   = wn;
    const int ln15 = lane & 15;
    const int lg   = lane >> 4;   // 0..3

    // ---- one-time: edge weights (sender-major), invariant across phases ----
    #pragma unroll
    for (int it = 0; it < 2; ++it) {
        // smWgt[k][rv][s] ; diagonal s==r -> 0
        int i = tid + it * 512;
        int k = i >> 9, m = i & 511;
        int rw = m >> 6, s = m & 63;
        int r = r0 + rw;
        float w = 0.0f;
        if (s != r) {
            int j = s - (s > r ? 1 : 0);
            w = edges[((size_t)b * EE + r * 63 + j) * KK + k];
        }
        smWgt[i] = w;
    }

    // swizzled u read offsets: byte = s*512 + ((kc*64 + lg*16) ^ ((s&7)<<4)),
    // s = mi*16 + ln15 -> s&7 = ln15&7 (per-lane constant).
    const int xm45 = (ln15 & 3) << 4;
    const int xm6  = (ln15 & 4) << 4;
    int uoff[4];
    #pragma unroll
    for (int mi = 0; mi < 4; ++mi) {
        int s = mi * 16 + ln15;
        uoff[mi] = s * 512 + ((lg * 16) ^ xm45);
    }

    float* xc = xA;
    float* xn = xB;
    unsigned phase = 0;

    #pragma unroll 1
    for (int step = 0; step < NSTEP; ++step) {
        const float dt = load_dt(ts, scp, step);
        #pragma unroll 1
        for (int s = 0; s < 4; ++s) {
            const float cc = (s == 0) ? 0.0f : ((s == 3) ? 1.0f : 0.5f);
            const float* kprev = (s == 0) ? xc : ((s == 1) ? k1 : ((s == 2) ? k2 : k3));
            float* kout = (s == 0) ? k1 : ((s == 1) ? k2 : k3);   // s==3 unused

            // ---- P0: y (all 64 nodes) ----
            if (tid < 256) {
                int gi = (b * NN) * FF + tid;           // tid = n*4+f
                float y = xc[gi];
                if (s != 0) y += cc * dt * kprev[gi];
                smY[tid] = scrub(y);
            }

            float rsA[8], rsB[8];         // col-half 0 / 1, accumulated across k
            #pragma unroll
            for (int ni = 0; ni < 8; ++ni) { rsA[ni] = 0.0f; rsB[ni] = 0.0f; }

            __syncthreads();              // smY ready (wgt covered on first phase)

            // ---- build k=0 into buf0 ----
            build_uk(smem, 0, 0, tid, W1g, smY);
            build_vbh(smVBH, 0, 0, tid, r0, W1g, b1g, smY);
            __syncthreads();              // u0/vbh0 ready

            // ---- build k=1 (VALU) interleaves with GEMM k=0 (MFMA) ----
            build_uk(smem, 1, 1, tid, W1g, smY);
            build_vbh(smVBH, 1, 1, tid, r0, W1g, b1g, smY);
            gemm_half(smem, 0, 0, rv, 0, W2F, b2g, smWgt, lane, ln15, lg, uoff, xm6, rsA);
            gemm_half(smem, 0, 0, rv, 1, W2F, b2g, smWgt, lane, ln15, lg, uoff, xm6, rsB);
            __syncthreads();              // u1/vbh1 ready; buf0 dead from here on
            gemm_half(smem, 1, 1, rv, 0, W2F, b2g, smWgt, lane, ln15, lg, uoff, xm6, rsA);
            gemm_half(smem, 1, 1, rv, 1, W2F, b2g, smWgt, lane, ln15, lg, uoff, xm6, rsB);

            // ---- reduce over lg (senders) + write agg row directly as f16 A-tile ----
            #pragma unroll
            for (int ni = 0; ni < 8; ++ni) {
                rsA[ni] += __shfl_xor(rsA[ni], 16, 64);
                rsA[ni] += __shfl_xor(rsA[ni], 32, 64);
                rsB[ni] += __shfl_xor(rsB[ni], 16, 64);
                rsB[ni] += __shfl_xor(rsB[ni], 32, 64);
            }
            // augH aliases buf0 (dead since the mid-barrier). rows 8..15 / cols
            // 260..287 stay finite garbage — zero-padded Wo1F kills cols >=260;
            // rows >=8 never read back (MFMA rows independent).
            _Float16* smAugH = (_Float16*)(smem + OFF_AUGH);  // [16][296]
            if (lane < 16) {
                #pragma unroll
                for (int ni = 0; ni < 8; ++ni) {
                    smAugH[rv * 296 + 4   + ni * 16 + ln15] = (_Float16)rsA[ni];
                    smAugH[rv * 296 + 132 + ni * 16 + ln15] = (_Float16)rsB[ni];
                }
            } else if (lg == 1 && ln15 < 4) {
                smAugH[rv * 296 + ln15] = (_Float16)smY[(r0 + rv) * 4 + ln15];
            }
            __syncthreads();              // augH ready

            // ======== phase D: node MLP via f16 MFMA (rows r0..r0+7) ========
            _Float16* smP1H = (_Float16*)(smem + OFF_P1H);   // [16][264] (256 used)
            float*    smP2  = (float*)(smem + OFF_P2);       // [16][256]

            const int ot0 = wn * 2, ot1 = ot0 + 1;   // each wave owns two 16-col tiles

            // ---- L1: aug16 @ Wo1F (K=288, 9 k-tiles) + bo1, relu -> P1H f16 ----
            {
                float b0 = bo1[ot0 * 16 + ln15], b1v = bo1[ot1 * 16 + ln15];
                f32x4v a0 = {b0, b0, b0, b0}, a1 = {b1v, b1v, b1v, b1v};
                const _Float16* bb0 = Wo1F + (size_t)(ot0 * 9) * 512 + lane * 8;
                const _Float16* bb1 = Wo1F + (size_t)(ot1 * 9) * 512 + lane * 8;
                #pragma unroll
                for (int kc = 0; kc < 9; ++kc) {
                    f16x8 av  = *(const f16x8*)(smAugH + ln15 * 296 + kc * 32 + lg * 8);
                    f16x8 bf0 = *(const f16x8*)(bb0 + kc * 512);
                    f16x8 bf1 = *(const f16x8*)(bb1 + kc * 512);
                    a0 = __builtin_amdgcn_mfma_f32_16x16x32_f16(av, bf0, a0, 0, 0, 0);
                    a1 = __builtin_amdgcn_mfma_f32_16x16x32_f16(av, bf1, a1, 0, 0, 0);
                }
                // P1H disjoint from augH -> no barrier needed before these writes
                #pragma unroll
                for (int rr = 0; rr < 4; ++rr) {
                    int row = lg * 4 + rr;            // C/D: col = lane&15, row = lg*4+rr
                    smP1H[row * 264 + ot0 * 16 + ln15] = (_Float16)fmaxf(a0[rr], 0.0f);
                    smP1H[row * 264 + ot1 * 16 + ln15] = (_Float16)fmaxf(a1[rr], 0.0f);
                }
            }
            __syncthreads();
            // ---- L2: P1 @ Wo2F (K=256, 8 k-tiles) + bo2, relu -> P2 f32 ----
            {
                float b0 = bo2[ot0 * 16 + ln15], b1v = bo2[ot1 * 16 + ln15];
                f32x4v a0 = {b0, b0, b0, b0}, a1 = {b1v, b1v, b1v, b1v};
                const _Float16* bb0 = Wo2F + (size_t)(ot0 * 8) * 512 + lane * 8;
                const _Float16* bb1 = Wo2F + (size_t)(ot1 * 8) * 512 + lane * 8;
                #pragma unroll
                for (int kc = 0; kc < 8; ++kc) {
                    f16x8 av  = *(const f16x8*)(smP1H + ln15 * 264 + kc * 32 + lg * 8);
                    f16x8 bf0 = *(const f16x8*)(bb0 + kc * 512);
                    f16x8 bf1 = *(const f16x8*)(bb1 + kc * 512);
                    a0 = __builtin_amdgcn_mfma_f32_16x16x32_f16(av, bf0, a0, 0, 0, 0);
                    a1 = __builtin_amdgcn_mfma_f32_16x16x32_f16(av, bf1, a1, 0, 0, 0);
                }
                #pragma unroll
                for (int rr = 0; rr < 4; ++rr) {
                    int row = lg * 4 + rr;
                    smP2[row * 256 + ot0 * 16 + ln15] = fmaxf(a0[rr], 0.0f);
                    smP2[row * 256 + ot1 * 16 + ln15] = fmaxf(a1[rr], 0.0f);
                }
            }
            __syncthreads();
            // ---- L3 (256 -> 4) + residual + RK4 tail ----
            {
                int rr = tid >> 6, f = (tid >> 4) & 3, hs = tid & 15;  // 1 wave/row
                float part = 0.0f;
                #pragma unroll
                for (int j = 0; j < 16; ++j) {
                    int h = hs + j * 16;
                    part += smP2[rr * 256 + h] * Wo3[h * 4 + f];
                }
                part += __shfl_xor(part, 8, 64);
                part += __shfl_xor(part, 4, 64);
                part += __shfl_xor(part, 2, 64);
                part += __shfl_xor(part, 1, 64);
                if (hs == 0) {
                    int grow = b * NN + r0 + rr;
                    int gi   = grow * 4 + f;
                    float y = smY[(r0 + rr) * 4 + f];
                    float knew = scrub(y + bo3[f] + part);    // f(y) = y + p
                    if (s < 3) {
                        kout[gi] = knew;
                    } else {
                        float xv = scrub(xc[gi] + (dt * (1.0f / 6.0f)) *
                                   (k1[gi] + 2.0f * k2[gi] + 2.0f * k3[gi] + knew));
                        xn[gi] = xv;
                        // out layout (B, N, NSTEP, F): row = b*64+n
                        outp[(size_t)grow * NSTEP * FF + step * FF + f] = xv;
                    }
                }
            }

            ++phase;
            if (phase < 4u * NSTEP) gbar(gcnt, phase * 256u);
        }
        float* t = xc; xc = xn; xn = t;
    }
}

// Pre-swizzle W2 -> fragment-major W2F (verified): chunk (k,ot,kc) is
// 1 KiB; lane l holds B[o = ot*16 + (l&15)][h = kc*32 + (l>>4)*8 + e]
__global__ void swizzle_w2(const float* __restrict__ W2, _Float16* __restrict__ W2F)
{
    int idx = blockIdx.x * 256 + threadIdx.x;       // 0 .. 131071
    int k   = idx >> 16;
    int rem = idx & 65535;
    int ch  = rem >> 9;
    int pos = rem & 511;
    int ot  = ch >> 3, kc = ch & 7;
    int l   = pos >> 3, e = pos & 7;
    int o   = ot * 16 + (l & 15);
    int h   = kc * 32 + (l >> 4) * 8 + e;
    W2F[idx] = (_Float16)W2[(size_t)(k * 256 + h) * 256 + o];
}

// Wo1 [260][256] -> fragment-major f16, K padded to 288 (zeros).
__global__ void swizzle_wo1(const float* __restrict__ Wo1, _Float16* __restrict__ Wo1F)
{
    int idx = blockIdx.x * 256 + threadIdx.x;       // 0 .. 73727
    int ch = idx >> 9, pos = idx & 511;
    int ot = ch / 9, kc = ch - ot * 9;
    int l = pos >> 3, e = pos & 7;
    int k = kc * 32 + (l >> 4) * 8 + e;
    int o = ot * 16 + (l & 15);
    Wo1F[idx] = (k < 260) ? (_Float16)Wo1[(size_t)k * 256 + o] : (_Float16)0.0f;
}

// Wo2 [256][256] -> fragment-major f16.
__global__ void swizzle_wo2(const float* __restrict__ Wo2, _Float16* __restrict__ Wo2F)
{
    int idx = blockIdx.x * 256 + threadIdx.x;       // 0 .. 65535
    int ch = idx >> 9, pos = idx & 511;
    int ot = ch >> 3, kc = ch & 7;
    int l = pos >> 3, e = pos & 7;
    int k = kc * 32 + (l >> 4) * 8 + e;
    int o = ot * 16 + (l & 15);
    Wo2F[idx] = (_Float16)Wo2[(size_t)k * 256 + o];
}

__global__ void init_x(const float* __restrict__ inp, float* __restrict__ x0,
                       unsigned* __restrict__ gcnt)
{
    int i = blockIdx.x * 256 + threadIdx.x;   // i = (b*64+n)*4+f
    if (i == 0) *gcnt = 0u;                   // reset grid-barrier counter each replay
    if (i < BB * NN * FF) {
        int f = i & 3, bn = i >> 2;
        x0[i] = scrub(inp[(size_t)(bn * TT) * FF + f]);   // inputs[b][n][0][f]
    }
}

static int find_input(const int* in_sizes, int n_in, int want, unsigned char* used, int dflt) {
    if (dflt >= 0 && dflt < n_in && in_sizes[dflt] == want && !used[dflt]) { used[dflt] = 1; return dflt; }
    for (int i = 0; i < n_in; ++i)
        if (!used[i] && in_sizes[i] == want) { used[i] = 1; return i; }
    return dflt;
}

extern "C" void kernel_launch(void* const* d_in, const int* in_sizes, int n_in,
                              void* d_out, int out_size, void* d_ws, size_t ws_size,
                              hipStream_t stream)
{
    unsigned char used[64] = {0};
    int iInp = find_input(in_sizes, n_in, BB*NN*TT*FF, used, 0);
    int iEdg = find_input(in_sizes, n_in, BB*EE*KK,    used, 1);
    (void)find_input(in_sizes, n_in, EE*NN, used, 2);              // rel_rec (unused)
    (void)find_input(in_sizes, n_in, EE*NN, used, 3);              // rel_send (unused)
    int iW1  = find_input(in_sizes, n_in, KK*8*256,  used, 4);
    int ib1  = find_input(in_sizes, n_in, KK*256,    used, 5);
    int iW2  = find_input(in_sizes, n_in, KK*256*256,used, 6);
    int ib2  = find_input(in_sizes, n_in, KK*256,    used, 7);
    int iWo1 = find_input(in_sizes, n_in, 260*256,   used, 8);
    int ibo1 = find_input(in_sizes, n_in, 256,       used, 9);
    int iWo2 = find_input(in_sizes, n_in, 256*256,   used, 10);
    int ibo2 = find_input(in_sizes, n_in, 256,       used, 11);
    int iWo3 = find_input(in_sizes, n_in, 256*4,     used, 12);
    int ibo3 = find_input(in_sizes, n_in, 4,         used, 13);
    int iTs  = find_input(in_sizes, n_in, TT,        used, 14);
    (void)find_input(in_sizes, n_in, 1, used, 15);                 // pred_steps
    int iSc  = find_input(in_sizes, n_in, 1,         used, 16);    // scale

    const float* inputs = (const float*)d_in[iInp];
    const float* edges  = (const float*)d_in[iEdg];
    const float* W1  = (const float*)d_in[iW1];
    const float* b1  = (const float*)d_in[ib1];
    const float* W2  = (const float*)d_in[iW2];
    const float* b2  = (const float*)d_in[ib2];
    const float* Wo1 = (const float*)d_in[iWo1];
    const float* bo1 = (const float*)d_in[ibo1];
    const float* Wo2 = (const float*)d_in[iWo2];
    const float* bo2 = (const float*)d_in[ibo2];
    const float* Wo3 = (const float*)d_in[iWo3];
    const float* bo3 = (const float*)d_in[ibo3];
    const float* ts  = (const float*)d_in[iTs];
    const void*  scp = d_in[iSc];

    char* ws = (char*)d_ws;
    _Float16* W2F  = (_Float16*)ws;                       // 262144 B
    _Float16* Wo1F = (_Float16*)(ws + 262144);            // 147456 B
    _Float16* Wo2F = (_Float16*)(ws + 409600);            // 131072 B
    float* xA  = (float*)(ws + 540672);
    float* xB  = (float*)(ws + 540672 + 1 * 32768);
    float* k1  = (float*)(ws + 540672 + 2 * 32768);
    float* k2  = (float*)(ws + 540672 + 3 * 32768);
    float* k3  = (float*)(ws + 540672 + 4 * 32768);
    unsigned* gcnt = (unsigned*)(ws + 540672 + 5 * 32768);

    float* outp = (float*)d_out;   // f32 output

    (void)hipFuncSetAttribute((const void*)ode_kernel,
        hipFuncAttributeMaxDynamicSharedMemorySize, SMEM2);

    swizzle_w2<<<dim3(512), dim3(256), 0, stream>>>(W2, W2F);
    swizzle_wo1<<<dim3(288), dim3(256), 0, stream>>>(Wo1, Wo1F);
    swizzle_wo2<<<dim3(256), dim3(256), 0, stream>>>(Wo2, Wo2F);
    init_x<<<dim3(32), dim3(256), 0, stream>>>(inputs, xA, gcnt);

    ode_kernel<<<dim3(256), dim3(512), SMEM2, stream>>>(
        edges, W1, b1, W2F, b2, Wo1F, bo1, Wo2F, bo2, Wo3, bo3,
        ts, scp, xA, xB, k1, k2, k3, outp, gcnt);
}

// Round 11
// 7608.709 us; speedup vs baseline: 1.0650x; 1.0650x over previous
//
#include <hip/hip_runtime.h>

// Problem constants (fixed by setup_inputs)
#define BB 32
#define NN 64
#define TT 11
#define FF 4
#define KK 2
#define EE 4032      // N*(N-1)
#define NSTEP 10

typedef _Float16 f16x8 __attribute__((ext_vector_type(8)));
typedef float    f32x4v __attribute__((ext_vector_type(4)));

// ---- fused kernel LDS (512 thr, 8 receivers, grid 256 = 1 block/CU) ----
// phase C: u dbuf [2][64][512B XOR-swz] 64K | vbh dbuf [2][8][256]f16 8K |
//          y [64][4]f32 1K | wgt [2][8][64]f32 4K  (wgt persists across all phases)
// phase D aliases the (dead) u region: augH [16][296]f16 9472 | P1H [16][264]f16 8448 |
//          P2 [16][256]f32 16384  (total 34304 < 65536)
#define OFF_U0   0
#define OFF_VB   65536
#define OFF_Y    73728
#define OFF_WGT  74752
#define SMEM2    78848
#define OFF_AUGH 0
#define OFF_P1H  9472
#define OFF_P2   17920

__device__ __forceinline__ float scrub(float v) {
    return fminf(fmaxf(v, -3.0e4f), 3.0e4f);   // inactive when correct (|x| <~ 600)
}

__device__ __forceinline__ float load_dt(const float* ts, const void* scp, int step) {
    float t0 = ts[step], t1 = ts[step + 1];
    int w = ((const int*)scp)[0];
    float scl;
    if (w > 0 && w < 1000000) scl = (float)w;            // int32 (live path)
    else {
        float f = __int_as_float(w);
        scl = (f > 0.5f && f < 1.0e6f) ? f : 10.0f;
    }
    return (t1 - t0) / scl;
}

// Per-BATCH barrier (8 blocks, own padded cacheline). v11 fix of the round-10
// disaster: spin uses agent-scope atomic LOADS (concurrently served at the
// coherence point, no RMW cacheline ping-pong) and the domain is 8 blocks, not
// 256 -> no convoy, no L3 storm. threadfence release/acquire pattern is the one
// correctness-validated in round 10 (passed).
__device__ __forceinline__ void batch_bar(unsigned* cnt, unsigned goal) {
    __syncthreads();
    if (threadIdx.x == 0) {
        __threadfence();                         // release this block's global writes
        atomicAdd(cnt, 1u);                      // one RMW per block per phase
        while (__hip_atomic_load(cnt, __ATOMIC_RELAXED, __HIP_MEMORY_SCOPE_AGENT) < goal)
            __builtin_amdgcn_s_sleep(1);
        __threadfence();                         // acquire others' writes
    }
    __syncthreads();
}

// u-build (512 thr): u[s][h] = sum_f y_s[f] * W1send[k][f][h], f16, XOR-swizzled rows.
__device__ __forceinline__ void build_uk(char* smem, int buf, int k, int tid,
    const float* __restrict__ W1g, const float* smY)
{
    int hg = tid & 31, sb = tid >> 5;          // sb = 0..15
    const float* w1p = W1g + k * 2048 + hg * 8;
    f32x4v wA[4], wB[4];
    #pragma unroll
    for (int f = 0; f < 4; ++f) {
        wA[f] = *(const f32x4v*)(w1p + f * 256);
        wB[f] = *(const f32x4v*)(w1p + f * 256 + 4);
    }
    const int swz = (hg * 16) ^ ((sb & 7) << 4);   // s&7 == sb&7 (it*16 ≡ 0 mod 8)
    char* ub = smem + OFF_U0 + buf * 32768;
    #pragma unroll
    for (int it = 0; it < 4; ++it) {
        int s = sb + it * 16;
        f32x4v yv = *(const f32x4v*)(smY + s * 4);
        f16x8 uv;
        #pragma unroll
        for (int e = 0; e < 4; ++e) {
            float vA = yv[0]*wA[0][e] + yv[1]*wA[1][e] + yv[2]*wA[2][e] + yv[3]*wA[3][e];
            float vB = yv[0]*wB[0][e] + yv[1]*wB[1][e] + yv[2]*wB[2][e] + yv[3]*wB[3][e];
            uv[e]     = (_Float16)vA;
            uv[e + 4] = (_Float16)vB;
        }
        *(f16x8*)(ub + s * 512 + swz) = uv;
    }
}

// vbh[buf][rv][h] = f16( b1 + sum_f y_recv[f] * W1recv[k][f][h] ), rv = 0..7
__device__ __forceinline__ void build_vbh(_Float16* smVBH, int buf, int k, int tid, int r0,
    const float* __restrict__ W1g, const float* __restrict__ b1g, const float* smY)
{
    #pragma unroll
    for (int it = 0; it < 4; ++it) {
        int i = tid + it * 512;
        int rv = i >> 8, h = i & 255;
        float acch = b1g[k * 256 + h];
        #pragma unroll
        for (int f = 0; f < 4; ++f)
            acch += smY[(r0 + rv) * 4 + f] * W1g[k * 2048 + (4 + f) * 256 + h];
        smVBH[buf * 2048 + i] = (_Float16)acch;
    }
}

// One GEMM half-pass: wave owns ONE receiver rv; 64 sender-rows (4 mi) x 128 cols
// (col-half ch2), one k. Per kc: 4 u-reads + 1 vb-read feed 32 MFMAs.
// relu(acc)*w accumulated into rsum[8] registers (across both k).
__device__ __forceinline__ void gemm_half(char* smem, int buf, int k, int rv, int ch2,
    const _Float16* __restrict__ W2F, const float* __restrict__ b2g,
    const float* smWgt,
    int lane, int ln15, int lg, const int* uoff, int xm6,
    float rsum[8])
{
    const _Float16* smVBH = (const _Float16*)(smem + OFF_VB);

    float bv[8];
    #pragma unroll
    for (int ni = 0; ni < 8; ++ni)
        bv[ni] = b2g[k * 256 + ch2 * 128 + ni * 16 + ln15];

    f32x4v acc[4][8];         // b2 folded into init; 128 AGPR
    #pragma unroll
    for (int mi = 0; mi < 4; ++mi)
        #pragma unroll
        for (int ni = 0; ni < 8; ++ni)
            acc[mi][ni] = (f32x4v){bv[ni], bv[ni], bv[ni], bv[ni]};

    const _Float16* bbase = W2F + ((size_t)((k * 16 + ch2 * 8) * 8)) * 512 + lane * 8;
    const char* ubase = smem + OFF_U0 + buf * 32768;
    const _Float16* vbase = smVBH + buf * 2048 + rv * 256;

    #pragma unroll
    for (int kc = 0; kc < 8; ++kc) {
        f16x8 bfr[8];
        #pragma unroll
        for (int ni = 0; ni < 8; ++ni)
            bfr[ni] = *(const f16x8*)(bbase + (size_t)(ni * 8 + kc) * 512);
        f16x8 vbv = *(const f16x8*)(vbase + kc * 32 + lg * 8);
        const int kco = (kc * 64) ^ xm6;
        f16x8 af[4];
        f16x8 z = {};
        #pragma unroll
        for (int mi = 0; mi < 4; ++mi) {
            f16x8 uv = *(const f16x8*)(ubase + uoff[mi] + kco);
            af[mi] = __builtin_elementwise_max(uv + vbv, z);
        }
        __builtin_amdgcn_s_setprio(1);
        #pragma unroll
        for (int mi = 0; mi < 4; ++mi)
            #pragma unroll
            for (int ni = 0; ni < 8; ++ni)
                acc[mi][ni] = __builtin_amdgcn_mfma_f32_16x16x32_f16(
                    af[mi], bfr[ni], acc[mi][ni], 0, 0, 0);
        __builtin_amdgcn_s_setprio(0);
    }

    // ---- epilogue: relu * edge_w into rsum regs ----
    #pragma unroll
    for (int mi = 0; mi < 4; ++mi) {
        #pragma unroll
        for (int rr = 0; rr < 4; ++rr) {
            // C/D: col = lane&15, row = lg*4 + rr  [m89/m91]; sender s = mi*16 + row
            float w = smWgt[k * 512 + rv * 64 + mi * 16 + lg * 4 + rr];
            #pragma unroll
            for (int ni = 0; ni < 8; ++ni)
                rsum[ni] += fmaxf(acc[mi][ni][rr], 0.0f) * w;
        }
    }
}

// v11: whole RK4 solve in ONE kernel with PER-BATCH sync (8 blocks), not grid-wide.
// Batches are independent; the only cross-block data at a phase boundary is the
// batch's 1 KB y/k-state -> 8-block barrier per phase. Block swizzle co-locates a
// batch's 8 blocks on one XCD (p%8 heuristic; perf-only). Phase body = v9 verbatim
// (best verified, 1535 us). Edge weights + swizzle offsets set up ONCE.
__global__ __launch_bounds__(512, 2)
void ode_kernel(const float* __restrict__ edges, const float* __restrict__ W1g,
    const float* __restrict__ b1g,   const _Float16* __restrict__ W2F,
    const float* __restrict__ b2g,
    const _Float16* __restrict__ Wo1F, const float* __restrict__ bo1,
    const _Float16* __restrict__ Wo2F, const float* __restrict__ bo2,
    const float* __restrict__ Wo3, const float* __restrict__ bo3,
    const float* __restrict__ ts,  const void* __restrict__ scp,
    float* __restrict__ xA, float* __restrict__ xB,
    float* __restrict__ k1, float* __restrict__ k2, float* __restrict__ k3,
    float* __restrict__ outp, unsigned* __restrict__ gcnt)
{
    extern __shared__ char smem[];
    _Float16* smVBH = (_Float16*)(smem + OFF_VB);
    float*  smY   = (float*)(smem + OFF_Y);
    float*  smWgt = (float*)(smem + OFF_WGT);

    const int tid = threadIdx.x;
    // XCD-coherent swizzle: batch b's 8 blocks all have blockIdx%8 == b/4.
    const int x8 = blockIdx.x & 7;
    const int j8 = blockIdx.x >> 3;
    const int b  = x8 * 4 + (j8 & 3);
    const int rg = j8 >> 2;
    const int r0 = rg * 8;
    unsigned* bar = gcnt + b * 16;    // one padded cacheline per batch

    const int lane = tid & 63;
    const int wn   = tid >> 6;    // 8 waves: wave wn owns receiver rv = wn
    const int rv   = wn;
    const int ln15 = lane & 15;
    const int lg   = lane >> 4;   // 0..3

    // ---- one-time: edge weights (sender-major), invariant across phases ----
    #pragma unroll
    for (int it = 0; it < 2; ++it) {
        // smWgt[k][rv][s] ; diagonal s==r -> 0
        int i = tid + it * 512;
        int k = i >> 9, m = i & 511;
        int rw = m >> 6, s = m & 63;
        int r = r0 + rw;
        float w = 0.0f;
        if (s != r) {
            int j = s - (s > r ? 1 : 0);
            w = edges[((size_t)b * EE + r * 63 + j) * KK + k];
        }
        smWgt[i] = w;
    }

    // swizzled u read offsets: byte = s*512 + ((kc*64 + lg*16) ^ ((s&7)<<4)),
    // s = mi*16 + ln15 -> s&7 = ln15&7 (per-lane constant).
    const int xm45 = (ln15 & 3) << 4;
    const int xm6  = (ln15 & 4) << 4;
    int uoff[4];
    #pragma unroll
    for (int mi = 0; mi < 4; ++mi) {
        int s = mi * 16 + ln15;
        uoff[mi] = s * 512 + ((lg * 16) ^ xm45);
    }

    float* xc = xA;
    float* xn = xB;
    unsigned phase = 0;

    #pragma unroll 1
    for (int step = 0; step < NSTEP; ++step) {
        const float dt = load_dt(ts, scp, step);
        #pragma unroll 1
        for (int s = 0; s < 4; ++s) {
            const float cc = (s == 0) ? 0.0f : ((s == 3) ? 1.0f : 0.5f);
            const float* kprev = (s == 0) ? xc : ((s == 1) ? k1 : ((s == 2) ? k2 : k3));
            float* kout = (s == 0) ? k1 : ((s == 1) ? k2 : k3);   // s==3 unused

            // ---- P0: y (all 64 nodes) ----
            if (tid < 256) {
                int gi = (b * NN) * FF + tid;           // tid = n*4+f
                float y = xc[gi];
                if (s != 0) y += cc * dt * kprev[gi];
                smY[tid] = scrub(y);
            }

            float rsA[8], rsB[8];         // col-half 0 / 1, accumulated across k
            #pragma unroll
            for (int ni = 0; ni < 8; ++ni) { rsA[ni] = 0.0f; rsB[ni] = 0.0f; }

            __syncthreads();              // smY ready (wgt covered on first phase)

            // ---- build k=0 into buf0 ----
            build_uk(smem, 0, 0, tid, W1g, smY);
            build_vbh(smVBH, 0, 0, tid, r0, W1g, b1g, smY);
            __syncthreads();              // u0/vbh0 ready

            // ---- build k=1 (VALU) interleaves with GEMM k=0 (MFMA) ----
            build_uk(smem, 1, 1, tid, W1g, smY);
            build_vbh(smVBH, 1, 1, tid, r0, W1g, b1g, smY);
            gemm_half(smem, 0, 0, rv, 0, W2F, b2g, smWgt, lane, ln15, lg, uoff, xm6, rsA);
            gemm_half(smem, 0, 0, rv, 1, W2F, b2g, smWgt, lane, ln15, lg, uoff, xm6, rsB);
            __syncthreads();              // u1/vbh1 ready; buf0 dead from here on
            gemm_half(smem, 1, 1, rv, 0, W2F, b2g, smWgt, lane, ln15, lg, uoff, xm6, rsA);
            gemm_half(smem, 1, 1, rv, 1, W2F, b2g, smWgt, lane, ln15, lg, uoff, xm6, rsB);

            // ---- reduce over lg (senders) + write agg row directly as f16 A-tile ----
            #pragma unroll
            for (int ni = 0; ni < 8; ++ni) {
                rsA[ni] += __shfl_xor(rsA[ni], 16, 64);
                rsA[ni] += __shfl_xor(rsA[ni], 32, 64);
                rsB[ni] += __shfl_xor(rsB[ni], 16, 64);
                rsB[ni] += __shfl_xor(rsB[ni], 32, 64);
            }
            // augH aliases buf0 (dead since the mid-barrier). rows 8..15 / cols
            // 260..287 stay finite garbage — zero-padded Wo1F kills cols >=260;
            // rows >=8 never read back (MFMA rows independent).
            _Float16* smAugH = (_Float16*)(smem + OFF_AUGH);  // [16][296]
            if (lane < 16) {
                #pragma unroll
                for (int ni = 0; ni < 8; ++ni) {
                    smAugH[rv * 296 + 4   + ni * 16 + ln15] = (_Float16)rsA[ni];
                    smAugH[rv * 296 + 132 + ni * 16 + ln15] = (_Float16)rsB[ni];
                }
            } else if (lg == 1 && ln15 < 4) {
                smAugH[rv * 296 + ln15] = (_Float16)smY[(r0 + rv) * 4 + ln15];
            }
            __syncthreads();              // augH ready

            // ======== phase D: node MLP via f16 MFMA (rows r0..r0+7) ========
            _Float16* smP1H = (_Float16*)(smem + OFF_P1H);   // [16][264] (256 used)
            float*    smP2  = (float*)(smem + OFF_P2);       // [16][256]

            const int ot0 = wn * 2, ot1 = ot0 + 1;   // each wave owns two 16-col tiles

            // ---- L1: aug16 @ Wo1F (K=288, 9 k-tiles) + bo1, relu -> P1H f16 ----
            {
                float b0 = bo1[ot0 * 16 + ln15], b1v = bo1[ot1 * 16 + ln15];
                f32x4v a0 = {b0, b0, b0, b0}, a1 = {b1v, b1v, b1v, b1v};
                const _Float16* bb0 = Wo1F + (size_t)(ot0 * 9) * 512 + lane * 8;
                const _Float16* bb1 = Wo1F + (size_t)(ot1 * 9) * 512 + lane * 8;
                #pragma unroll
                for (int kc = 0; kc < 9; ++kc) {
                    f16x8 av  = *(const f16x8*)(smAugH + ln15 * 296 + kc * 32 + lg * 8);
                    f16x8 bf0 = *(const f16x8*)(bb0 + kc * 512);
                    f16x8 bf1 = *(const f16x8*)(bb1 + kc * 512);
                    a0 = __builtin_amdgcn_mfma_f32_16x16x32_f16(av, bf0, a0, 0, 0, 0);
                    a1 = __builtin_amdgcn_mfma_f32_16x16x32_f16(av, bf1, a1, 0, 0, 0);
                }
                // P1H disjoint from augH -> no barrier needed before these writes
                #pragma unroll
                for (int rr = 0; rr < 4; ++rr) {
                    int row = lg * 4 + rr;            // C/D: col = lane&15, row = lg*4+rr
                    smP1H[row * 264 + ot0 * 16 + ln15] = (_Float16)fmaxf(a0[rr], 0.0f);
                    smP1H[row * 264 + ot1 * 16 + ln15] = (_Float16)fmaxf(a1[rr], 0.0f);
                }
            }
            __syncthreads();
            // ---- L2: P1 @ Wo2F (K=256, 8 k-tiles) + bo2, relu -> P2 f32 ----
            {
                float b0 = bo2[ot0 * 16 + ln15], b1v = bo2[ot1 * 16 + ln15];
                f32x4v a0 = {b0, b0, b0, b0}, a1 = {b1v, b1v, b1v, b1v};
                const _Float16* bb0 = Wo2F + (size_t)(ot0 * 8) * 512 + lane * 8;
                const _Float16* bb1 = Wo2F + (size_t)(ot1 * 8) * 512 + lane * 8;
                #pragma unroll
                for (int kc = 0; kc < 8; ++kc) {
                    f16x8 av  = *(const f16x8*)(smP1H + ln15 * 264 + kc * 32 + lg * 8);
                    f16x8 bf0 = *(const f16x8*)(bb0 + kc * 512);
                    f16x8 bf1 = *(const f16x8*)(bb1 + kc * 512);
                    a0 = __builtin_amdgcn_mfma_f32_16x16x32_f16(av, bf0, a0, 0, 0, 0);
                    a1 = __builtin_amdgcn_mfma_f32_16x16x32_f16(av, bf1, a1, 0, 0, 0);
                }
                #pragma unroll
                for (int rr = 0; rr < 4; ++rr) {
                    int row = lg * 4 + rr;
                    smP2[row * 256 + ot0 * 16 + ln15] = fmaxf(a0[rr], 0.0f);
                    smP2[row * 256 + ot1 * 16 + ln15] = fmaxf(a1[rr], 0.0f);
                }
            }
            __syncthreads();
            // ---- L3 (256 -> 4) + residual + RK4 tail ----
            {
                int rr = tid >> 6, f = (tid >> 4) & 3, hs = tid & 15;  // 1 wave/row
                float part = 0.0f;
                #pragma unroll
                for (int j = 0; j < 16; ++j) {
                    int h = hs + j * 16;
                    part += smP2[rr * 256 + h] * Wo3[h * 4 + f];
                }
                part += __shfl_xor(part, 8, 64);
                part += __shfl_xor(part, 4, 64);
                part += __shfl_xor(part, 2, 64);
                part += __shfl_xor(part, 1, 64);
                if (hs == 0) {
                    int grow = b * NN + r0 + rr;
                    int gi   = grow * 4 + f;
                    float y = smY[(r0 + rr) * 4 + f];
                    float knew = scrub(y + bo3[f] + part);    // f(y) = y + p
                    if (s < 3) {
                        kout[gi] = knew;
                    } else {
                        float xv = scrub(xc[gi] + (dt * (1.0f / 6.0f)) *
                                   (k1[gi] + 2.0f * k2[gi] + 2.0f * k3[gi] + knew));
                        xn[gi] = xv;
                        // out layout (B, N, NSTEP, F): row = b*64+n
                        outp[(size_t)grow * NSTEP * FF + step * FF + f] = xv;
                    }
                }
            }

            ++phase;
            if (phase < 4u * NSTEP) batch_bar(bar, phase * 8u);
        }
        float* t = xc; xc = xn; xn = t;
    }
}

// Pre-swizzle W2 -> fragment-major W2F (verified): chunk (k,ot,kc) is
// 1 KiB; lane l holds B[o = ot*16 + (l&15)][h = kc*32 + (l>>4)*8 + e]
__global__ void swizzle_w2(const float* __restrict__ W2, _Float16* __restrict__ W2F)
{
    int idx = blockIdx.x * 256 + threadIdx.x;       // 0 .. 131071
    int k   = idx >> 16;
    int rem = idx & 65535;
    int ch  = rem >> 9;
    int pos = rem & 511;
    int ot  = ch >> 3, kc = ch & 7;
    int l   = pos >> 3, e = pos & 7;
    int o   = ot * 16 + (l & 15);
    int h   = kc * 32 + (l >> 4) * 8 + e;
    W2F[idx] = (_Float16)W2[(size_t)(k * 256 + h) * 256 + o];
}

// Wo1 [260][256] -> fragment-major f16, K padded to 288 (zeros).
__global__ void swizzle_wo1(const float* __restrict__ Wo1, _Float16* __restrict__ Wo1F)
{
    int idx = blockIdx.x * 256 + threadIdx.x;       // 0 .. 73727
    int ch = idx >> 9, pos = idx & 511;
    int ot = ch / 9, kc = ch - ot * 9;
    int l = pos >> 3, e = pos & 7;
    int k = kc * 32 + (l >> 4) * 8 + e;
    int o = ot * 16 + (l & 15);
    Wo1F[idx] = (k < 260) ? (_Float16)Wo1[(size_t)k * 256 + o] : (_Float16)0.0f;
}

// Wo2 [256][256] -> fragment-major f16.
__global__ void swizzle_wo2(const float* __restrict__ Wo2, _Float16* __restrict__ Wo2F)
{
    int idx = blockIdx.x * 256 + threadIdx.x;       // 0 .. 65535
    int ch = idx >> 9, pos = idx & 511;
    int ot = ch >> 3, kc = ch & 7;
    int l = pos >> 3, e = pos & 7;
    int k = kc * 32 + (l >> 4) * 8 + e;
    int o = ot * 16 + (l & 15);
    Wo2F[idx] = (_Float16)Wo2[(size_t)k * 256 + o];
}

__global__ void init_x(const float* __restrict__ inp, float* __restrict__ x0,
                       unsigned* __restrict__ gcnt)
{
    int i = blockIdx.x * 256 + threadIdx.x;   // i = (b*64+n)*4+f
    if (i < 512) gcnt[i] = 0u;                // reset per-batch barrier counters each replay
    if (i < BB * NN * FF) {
        int f = i & 3, bn = i >> 2;
        x0[i] = scrub(inp[(size_t)(bn * TT) * FF + f]);   // inputs[b][n][0][f]
    }
}

static int find_input(const int* in_sizes, int n_in, int want, unsigned char* used, int dflt) {
    if (dflt >= 0 && dflt < n_in && in_sizes[dflt] == want && !used[dflt]) { used[dflt] = 1; return dflt; }
    for (int i = 0; i < n_in; ++i)
        if (!used[i] && in_sizes[i] == want) { used[i] = 1; return i; }
    return dflt;
}

extern "C" void kernel_launch(void* const* d_in, const int* in_sizes, int n_in,
                              void* d_out, int out_size, void* d_ws, size_t ws_size,
                              hipStream_t stream)
{
    unsigned char used[64] = {0};
    int iInp = find_input(in_sizes, n_in, BB*NN*TT*FF, used, 0);
    int iEdg = find_input(in_sizes, n_in, BB*EE*KK,    used, 1);
    (void)find_input(in_sizes, n_in, EE*NN, used, 2);              // rel_rec (unused)
    (void)find_input(in_sizes, n_in, EE*NN, used, 3);              // rel_send (unused)
    int iW1  = find_input(in_sizes, n_in, KK*8*256,  used, 4);
    int ib1  = find_input(in_sizes, n_in, KK*256,    used, 5);
    int iW2  = find_input(in_sizes, n_in, KK*256*256,used, 6);
    int ib2  = find_input(in_sizes, n_in, KK*256,    used, 7);
    int iWo1 = find_input(in_sizes, n_in, 260*256,   used, 8);
    int ibo1 = find_input(in_sizes, n_in, 256,       used, 9);
    int iWo2 = find_input(in_sizes, n_in, 256*256,   used, 10);
    int ibo2 = find_input(in_sizes, n_in, 256,       used, 11);
    int iWo3 = find_input(in_sizes, n_in, 256*4,     used, 12);
    int ibo3 = find_input(in_sizes, n_in, 4,         used, 13);
    int iTs  = find_input(in_sizes, n_in, TT,        used, 14);
    (void)find_input(in_sizes, n_in, 1, used, 15);                 // pred_steps
    int iSc  = find_input(in_sizes, n_in, 1,         used, 16);    // scale

    const float* inputs = (const float*)d_in[iInp];
    const float* edges  = (const float*)d_in[iEdg];
    const float* W1  = (const float*)d_in[iW1];
    const float* b1  = (const float*)d_in[ib1];
    const float* W2  = (const float*)d_in[iW2];
    const float* b2  = (const float*)d_in[ib2];
    const float* Wo1 = (const float*)d_in[iWo1];
    const float* bo1 = (const float*)d_in[ibo1];
    const float* Wo2 = (const float*)d_in[iWo2];
    const float* bo2 = (const float*)d_in[ibo2];
    const float* Wo3 = (const float*)d_in[iWo3];
    const float* bo3 = (const float*)d_in[ibo3];
    const float* ts  = (const float*)d_in[iTs];
    const void*  scp = d_in[iSc];

    char* ws = (char*)d_ws;
    _Float16* W2F  = (_Float16*)ws;                       // 262144 B
    _Float16* Wo1F = (_Float16*)(ws + 262144);            // 147456 B
    _Float16* Wo2F = (_Float16*)(ws + 409600);            // 131072 B
    float* xA  = (float*)(ws + 540672);
    float* xB  = (float*)(ws + 540672 + 1 * 32768);
    float* k1  = (float*)(ws + 540672 + 2 * 32768);
    float* k2  = (float*)(ws + 540672 + 3 * 32768);
    float* k3  = (float*)(ws + 540672 + 4 * 32768);
    unsigned* gcnt = (unsigned*)(ws + 540672 + 5 * 32768);   // 32 batches x 16 u32

    float* outp = (float*)d_out;   // f32 output

    (void)hipFuncSetAttribute((const void*)ode_kernel,
        hipFuncAttributeMaxDynamicSharedMemorySize, SMEM2);

    swizzle_w2<<<dim3(512), dim3(256), 0, stream>>>(W2, W2F);
    swizzle_wo1<<<dim3(288), dim3(256), 0, stream>>>(Wo1, Wo1F);
    swizzle_wo2<<<dim3(256), dim3(256), 0, stream>>>(Wo2, Wo2F);
    init_x<<<dim3(32), dim3(256), 0, stream>>>(inputs, xA, gcnt);

    ode_kernel<<<dim3(256), dim3(512), SMEM2, stream>>>(
        edges, W1, b1, W2F, b2, Wo1F, bo1, Wo2F, bo2, Wo3, bo3,
        ts, scp, xA, xB, k1, k2, k3, outp, gcnt);
}

// Round 12
// 7413.033 us; speedup vs baseline: 1.0931x; 1.0264x over previous
//
#include <hip/hip_runtime.h>

// Problem constants (fixed by setup_inputs)
#define BB 32
#define NN 64
#define TT 11
#define FF 4
#define KK 2
#define EE 4032      // N*(N-1)
#define NSTEP 10

typedef _Float16 f16x8 __attribute__((ext_vector_type(8)));
typedef float    f32x4v __attribute__((ext_vector_type(4)));

// ---- fused kernel LDS (512 thr, 8 receivers, grid 256 = 1 block/CU) ----
// phase C: u dbuf [2][64][512B XOR-swz] 64K | vbh dbuf [2][8][256]f16 8K |
//          y [64][4]f32 1K | wgt [2][8][64]f32 4K  (wgt persists across all phases)
// phase D aliases the (dead) u region: augH [16][296]f16 9472 | P1H [16][264]f16 8448 |
//          P2 [16][256]f32 16384  (total 34304 < 65536)
#define OFF_U0   0
#define OFF_VB   65536
#define OFF_Y    73728
#define OFF_WGT  74752
#define SMEM2    78848
#define OFF_AUGH 0
#define OFF_P1H  9472
#define OFF_P2   17920

__device__ __forceinline__ float scrub(float v) {
    return fminf(fmaxf(v, -3.0e4f), 3.0e4f);   // inactive when correct (|x| <~ 600)
}

__device__ __forceinline__ float load_dt(const float* ts, const void* scp, int step) {
    float t0 = ts[step], t1 = ts[step + 1];
    int w = ((const int*)scp)[0];
    float scl;
    if (w > 0 && w < 1000000) scl = (float)w;            // int32 (live path)
    else {
        float f = __int_as_float(w);
        scl = (f > 0.5f && f < 1.0e6f) ? f : 10.0f;
    }
    return (t1 - t0) / scl;
}

// Cross-block state passed via agent-scope RELAXED atomics: per-access coherence
// (sc0|sc1 -> served at the coherence point, never stale) with NO cache-wide
// invalidation. This is the round-11 fix: __threadfence's acquire emitted a
// buffer_inv that nuked the L2 every phase (FETCH 14.8 GB, 5x regression).
__device__ __forceinline__ float aload(const float* p) {
    return __hip_atomic_load(p, __ATOMIC_RELAXED, __HIP_MEMORY_SCOPE_AGENT);
}
__device__ __forceinline__ void astore(float* p, float v) {
    __hip_atomic_store(p, v, __ATOMIC_RELAXED, __HIP_MEMORY_SCOPE_AGENT);
}

// Per-BATCH barrier (8 blocks, own padded cacheline), fence-free:
//  - arrival: RELEASE fetch_add (vmcnt(0) drains the relaxed data stores, then the
//    RMW lands at the coherence point; release writes back, does NOT invalidate)
//  - wait: RELAXED agent loads (L3-served; no buffer_inv) + s_sleep backoff.
// Reader-side ordering: the spin's control dependency (branch on the loaded flag)
// orders the subsequent aload data reads; those also go to the coherence point.
__device__ __forceinline__ void batch_bar(unsigned* cnt, unsigned goal) {
    __syncthreads();
    if (threadIdx.x == 0) {
        __hip_atomic_fetch_add(cnt, 1u, __ATOMIC_RELEASE, __HIP_MEMORY_SCOPE_AGENT);
        while (__hip_atomic_load(cnt, __ATOMIC_RELAXED, __HIP_MEMORY_SCOPE_AGENT) < goal)
            __builtin_amdgcn_s_sleep(2);
    }
    __syncthreads();
}

// u-build (512 thr): u[s][h] = sum_f y_s[f] * W1send[k][f][h], f16, XOR-swizzled rows.
__device__ __forceinline__ void build_uk(char* smem, int buf, int k, int tid,
    const float* __restrict__ W1g, const float* smY)
{
    int hg = tid & 31, sb = tid >> 5;          // sb = 0..15
    const float* w1p = W1g + k * 2048 + hg * 8;
    f32x4v wA[4], wB[4];
    #pragma unroll
    for (int f = 0; f < 4; ++f) {
        wA[f] = *(const f32x4v*)(w1p + f * 256);
        wB[f] = *(const f32x4v*)(w1p + f * 256 + 4);
    }
    const int swz = (hg * 16) ^ ((sb & 7) << 4);   // s&7 == sb&7 (it*16 ≡ 0 mod 8)
    char* ub = smem + OFF_U0 + buf * 32768;
    #pragma unroll
    for (int it = 0; it < 4; ++it) {
        int s = sb + it * 16;
        f32x4v yv = *(const f32x4v*)(smY + s * 4);
        f16x8 uv;
        #pragma unroll
        for (int e = 0; e < 4; ++e) {
            float vA = yv[0]*wA[0][e] + yv[1]*wA[1][e] + yv[2]*wA[2][e] + yv[3]*wA[3][e];
            float vB = yv[0]*wB[0][e] + yv[1]*wB[1][e] + yv[2]*wB[2][e] + yv[3]*wB[3][e];
            uv[e]     = (_Float16)vA;
            uv[e + 4] = (_Float16)vB;
        }
        *(f16x8*)(ub + s * 512 + swz) = uv;
    }
}

// vbh[buf][rv][h] = f16( b1 + sum_f y_recv[f] * W1recv[k][f][h] ), rv = 0..7
__device__ __forceinline__ void build_vbh(_Float16* smVBH, int buf, int k, int tid, int r0,
    const float* __restrict__ W1g, const float* __restrict__ b1g, const float* smY)
{
    #pragma unroll
    for (int it = 0; it < 4; ++it) {
        int i = tid + it * 512;
        int rv = i >> 8, h = i & 255;
        float acch = b1g[k * 256 + h];
        #pragma unroll
        for (int f = 0; f < 4; ++f)
            acch += smY[(r0 + rv) * 4 + f] * W1g[k * 2048 + (4 + f) * 256 + h];
        smVBH[buf * 2048 + i] = (_Float16)acch;
    }
}

// One GEMM half-pass: wave owns ONE receiver rv; 64 sender-rows (4 mi) x 128 cols
// (col-half ch2), one k. Per kc: 4 u-reads + 1 vb-read feed 32 MFMAs.
// relu(acc)*w accumulated into rsum[8] registers (across both k).
__device__ __forceinline__ void gemm_half(char* smem, int buf, int k, int rv, int ch2,
    const _Float16* __restrict__ W2F, const float* __restrict__ b2g,
    const float* smWgt,
    int lane, int ln15, int lg, const int* uoff, int xm6,
    float rsum[8])
{
    const _Float16* smVBH = (const _Float16*)(smem + OFF_VB);

    float bv[8];
    #pragma unroll
    for (int ni = 0; ni < 8; ++ni)
        bv[ni] = b2g[k * 256 + ch2 * 128 + ni * 16 + ln15];

    f32x4v acc[4][8];         // b2 folded into init; 128 AGPR
    #pragma unroll
    for (int mi = 0; mi < 4; ++mi)
        #pragma unroll
        for (int ni = 0; ni < 8; ++ni)
            acc[mi][ni] = (f32x4v){bv[ni], bv[ni], bv[ni], bv[ni]};

    const _Float16* bbase = W2F + ((size_t)((k * 16 + ch2 * 8) * 8)) * 512 + lane * 8;
    const char* ubase = smem + OFF_U0 + buf * 32768;
    const _Float16* vbase = smVBH + buf * 2048 + rv * 256;

    #pragma unroll
    for (int kc = 0; kc < 8; ++kc) {
        f16x8 bfr[8];
        #pragma unroll
        for (int ni = 0; ni < 8; ++ni)
            bfr[ni] = *(const f16x8*)(bbase + (size_t)(ni * 8 + kc) * 512);
        f16x8 vbv = *(const f16x8*)(vbase + kc * 32 + lg * 8);
        const int kco = (kc * 64) ^ xm6;
        f16x8 af[4];
        f16x8 z = {};
        #pragma unroll
        for (int mi = 0; mi < 4; ++mi) {
            f16x8 uv = *(const f16x8*)(ubase + uoff[mi] + kco);
            af[mi] = __builtin_elementwise_max(uv + vbv, z);
        }
        __builtin_amdgcn_s_setprio(1);
        #pragma unroll
        for (int mi = 0; mi < 4; ++mi)
            #pragma unroll
            for (int ni = 0; ni < 8; ++ni)
                acc[mi][ni] = __builtin_amdgcn_mfma_f32_16x16x32_f16(
                    af[mi], bfr[ni], acc[mi][ni], 0, 0, 0);
        __builtin_amdgcn_s_setprio(0);
    }

    // ---- epilogue: relu * edge_w into rsum regs ----
    #pragma unroll
    for (int mi = 0; mi < 4; ++mi) {
        #pragma unroll
        for (int rr = 0; rr < 4; ++rr) {
            // C/D: col = lane&15, row = lg*4 + rr  [m89/m91]; sender s = mi*16 + row
            float w = smWgt[k * 512 + rv * 64 + mi * 16 + lg * 4 + rr];
            #pragma unroll
            for (int ni = 0; ni < 8; ++ni)
                rsum[ni] += fmaxf(acc[mi][ni][rr], 0.0f) * w;
        }
    }
}

// v12: whole RK4 solve in ONE kernel, per-batch sync, FENCE-FREE. Cross-block x/k
// state flows through agent-scope relaxed atomics (coherence-point access, no L2
// invalidation) -> weights stay L2-cached across all 40 phases. Phase body = v9
// verbatim (best verified, 1535 us). Edge weights + swizzle offsets set up ONCE.
__global__ __launch_bounds__(512, 2)
void ode_kernel(const float* __restrict__ edges, const float* __restrict__ W1g,
    const float* __restrict__ b1g,   const _Float16* __restrict__ W2F,
    const float* __restrict__ b2g,
    const _Float16* __restrict__ Wo1F, const float* __restrict__ bo1,
    const _Float16* __restrict__ Wo2F, const float* __restrict__ bo2,
    const float* __restrict__ Wo3, const float* __restrict__ bo3,
    const float* __restrict__ ts,  const void* __restrict__ scp,
    float* __restrict__ xA, float* __restrict__ xB,
    float* __restrict__ k1, float* __restrict__ k2, float* __restrict__ k3,
    float* __restrict__ outp, unsigned* __restrict__ gcnt)
{
    extern __shared__ char smem[];
    _Float16* smVBH = (_Float16*)(smem + OFF_VB);
    float*  smY   = (float*)(smem + OFF_Y);
    float*  smWgt = (float*)(smem + OFF_WGT);

    const int tid = threadIdx.x;
    // XCD-coherent swizzle: batch b's 8 blocks all have blockIdx%8 == b/4 ->
    // same XCD (blocks round-robin across XCDs). Keeps the batch's edges/state
    // in one L2 and gives defense-in-depth for the shared-state path.
    const int x8 = blockIdx.x & 7;
    const int j8 = blockIdx.x >> 3;
    const int b  = x8 * 4 + (j8 & 3);
    const int rg = j8 >> 2;
    const int r0 = rg * 8;
    unsigned* bar = gcnt + b * 16;    // one padded cacheline per batch

    const int lane = tid & 63;
    const int wn   = tid >> 6;    // 8 waves: wave wn owns receiver rv = wn
    const int rv   = wn;
    const int ln15 = lane & 15;
    const int lg   = lane >> 4;   // 0..3

    // ---- one-time: edge weights (sender-major), invariant across phases ----
    #pragma unroll
    for (int it = 0; it < 2; ++it) {
        // smWgt[k][rv][s] ; diagonal s==r -> 0
        int i = tid + it * 512;
        int k = i >> 9, m = i & 511;
        int rw = m >> 6, s = m & 63;
        int r = r0 + rw;
        float w = 0.0f;
        if (s != r) {
            int j = s - (s > r ? 1 : 0);
            w = edges[((size_t)b * EE + r * 63 + j) * KK + k];
        }
        smWgt[i] = w;
    }

    // swizzled u read offsets: byte = s*512 + ((kc*64 + lg*16) ^ ((s&7)<<4)),
    // s = mi*16 + ln15 -> s&7 = ln15&7 (per-lane constant).
    const int xm45 = (ln15 & 3) << 4;
    const int xm6  = (ln15 & 4) << 4;
    int uoff[4];
    #pragma unroll
    for (int mi = 0; mi < 4; ++mi) {
        int s = mi * 16 + ln15;
        uoff[mi] = s * 512 + ((lg * 16) ^ xm45);
    }

    float* xc = xA;
    float* xn = xB;
    unsigned phase = 0;

    #pragma unroll 1
    for (int step = 0; step < NSTEP; ++step) {
        const float dt = load_dt(ts, scp, step);
        #pragma unroll 1
        for (int s = 0; s < 4; ++s) {
            const float cc = (s == 0) ? 0.0f : ((s == 3) ? 1.0f : 0.5f);
            const float* kprev = (s == 0) ? xc : ((s == 1) ? k1 : ((s == 2) ? k2 : k3));
            float* kout = (s == 0) ? k1 : ((s == 1) ? k2 : k3);   // s==3 unused

            // ---- P0: y (all 64 nodes) — cross-block state via coherent loads ----
            if (tid < 256) {
                int gi = (b * NN) * FF + tid;           // tid = n*4+f
                float y = aload(xc + gi);
                if (s != 0) y += cc * dt * aload(kprev + gi);
                smY[tid] = scrub(y);
            }

            float rsA[8], rsB[8];         // col-half 0 / 1, accumulated across k
            #pragma unroll
            for (int ni = 0; ni < 8; ++ni) { rsA[ni] = 0.0f; rsB[ni] = 0.0f; }

            __syncthreads();              // smY ready (wgt covered on first phase)

            // ---- build k=0 into buf0 ----
            build_uk(smem, 0, 0, tid, W1g, smY);
            build_vbh(smVBH, 0, 0, tid, r0, W1g, b1g, smY);
            __syncthreads();              // u0/vbh0 ready

            // ---- build k=1 (VALU) interleaves with GEMM k=0 (MFMA) ----
            build_uk(smem, 1, 1, tid, W1g, smY);
            build_vbh(smVBH, 1, 1, tid, r0, W1g, b1g, smY);
            gemm_half(smem, 0, 0, rv, 0, W2F, b2g, smWgt, lane, ln15, lg, uoff, xm6, rsA);
            gemm_half(smem, 0, 0, rv, 1, W2F, b2g, smWgt, lane, ln15, lg, uoff, xm6, rsB);
            __syncthreads();              // u1/vbh1 ready; buf0 dead from here on
            gemm_half(smem, 1, 1, rv, 0, W2F, b2g, smWgt, lane, ln15, lg, uoff, xm6, rsA);
            gemm_half(smem, 1, 1, rv, 1, W2F, b2g, smWgt, lane, ln15, lg, uoff, xm6, rsB);

            // ---- reduce over lg (senders) + write agg row directly as f16 A-tile ----
            #pragma unroll
            for (int ni = 0; ni < 8; ++ni) {
                rsA[ni] += __shfl_xor(rsA[ni], 16, 64);
                rsA[ni] += __shfl_xor(rsA[ni], 32, 64);
                rsB[ni] += __shfl_xor(rsB[ni], 16, 64);
                rsB[ni] += __shfl_xor(rsB[ni], 32, 64);
            }
            // augH aliases buf0 (dead since the mid-barrier). rows 8..15 / cols
            // 260..287 stay finite garbage — zero-padded Wo1F kills cols >=260;
            // rows >=8 never read back (MFMA rows independent).
            _Float16* smAugH = (_Float16*)(smem + OFF_AUGH);  // [16][296]
            if (lane < 16) {
                #pragma unroll
                for (int ni = 0; ni < 8; ++ni) {
                    smAugH[rv * 296 + 4   + ni * 16 + ln15] = (_Float16)rsA[ni];
                    smAugH[rv * 296 + 132 + ni * 16 + ln15] = (_Float16)rsB[ni];
                }
            } else if (lg == 1 && ln15 < 4) {
                smAugH[rv * 296 + ln15] = (_Float16)smY[(r0 + rv) * 4 + ln15];
            }
            __syncthreads();              // augH ready

            // ======== phase D: node MLP via f16 MFMA (rows r0..r0+7) ========
            _Float16* smP1H = (_Float16*)(smem + OFF_P1H);   // [16][264] (256 used)
            float*    smP2  = (float*)(smem + OFF_P2);       // [16][256]

            const int ot0 = wn * 2, ot1 = ot0 + 1;   // each wave owns two 16-col tiles

            // ---- L1: aug16 @ Wo1F (K=288, 9 k-tiles) + bo1, relu -> P1H f16 ----
            {
                float b0 = bo1[ot0 * 16 + ln15], b1v = bo1[ot1 * 16 + ln15];
                f32x4v a0 = {b0, b0, b0, b0}, a1 = {b1v, b1v, b1v, b1v};
                const _Float16* bb0 = Wo1F + (size_t)(ot0 * 9) * 512 + lane * 8;
                const _Float16* bb1 = Wo1F + (size_t)(ot1 * 9) * 512 + lane * 8;
                #pragma unroll
                for (int kc = 0; kc < 9; ++kc) {
                    f16x8 av  = *(const f16x8*)(smAugH + ln15 * 296 + kc * 32 + lg * 8);
                    f16x8 bf0 = *(const f16x8*)(bb0 + kc * 512);
                    f16x8 bf1 = *(const f16x8*)(bb1 + kc * 512);
                    a0 = __builtin_amdgcn_mfma_f32_16x16x32_f16(av, bf0, a0, 0, 0, 0);
                    a1 = __builtin_amdgcn_mfma_f32_16x16x32_f16(av, bf1, a1, 0, 0, 0);
                }
                // P1H disjoint from augH -> no barrier needed before these writes
                #pragma unroll
                for (int rr = 0; rr < 4; ++rr) {
                    int row = lg * 4 + rr;            // C/D: col = lane&15, row = lg*4+rr
                    smP1H[row * 264 + ot0 * 16 + ln15] = (_Float16)fmaxf(a0[rr], 0.0f);
                    smP1H[row * 264 + ot1 * 16 + ln15] = (_Float16)fmaxf(a1[rr], 0.0f);
                }
            }
            __syncthreads();
            // ---- L2: P1 @ Wo2F (K=256, 8 k-tiles) + bo2, relu -> P2 f32 ----
            {
                float b0 = bo2[ot0 * 16 + ln15], b1v = bo2[ot1 * 16 + ln15];
                f32x4v a0 = {b0, b0, b0, b0}, a1 = {b1v, b1v, b1v, b1v};
                const _Float16* bb0 = Wo2F + (size_t)(ot0 * 8) * 512 + lane * 8;
                const _Float16* bb1 = Wo2F + (size_t)(ot1 * 8) * 512 + lane * 8;
                #pragma unroll
                for (int kc = 0; kc < 8; ++kc) {
                    f16x8 av  = *(const f16x8*)(smP1H + ln15 * 264 + kc * 32 + lg * 8);
                    f16x8 bf0 = *(const f16x8*)(bb0 + kc * 512);
                    f16x8 bf1 = *(const f16x8*)(bb1 + kc * 512);
                    a0 = __builtin_amdgcn_mfma_f32_16x16x32_f16(av, bf0, a0, 0, 0, 0);
                    a1 = __builtin_amdgcn_mfma_f32_16x16x32_f16(av, bf1, a1, 0, 0, 0);
                }
                #pragma unroll
                for (int rr = 0; rr < 4; ++rr) {
                    int row = lg * 4 + rr;
                    smP2[row * 256 + ot0 * 16 + ln15] = fmaxf(a0[rr], 0.0f);
                    smP2[row * 256 + ot1 * 16 + ln15] = fmaxf(a1[rr], 0.0f);
                }
            }
            __syncthreads();
            // ---- L3 (256 -> 4) + residual + RK4 tail ----
            {
                int rr = tid >> 6, f = (tid >> 4) & 3, hs = tid & 15;  // 1 wave/row
                float part = 0.0f;
                #pragma unroll
                for (int j = 0; j < 16; ++j) {
                    int h = hs + j * 16;
                    part += smP2[rr * 256 + h] * Wo3[h * 4 + f];
                }
                part += __shfl_xor(part, 8, 64);
                part += __shfl_xor(part, 4, 64);
                part += __shfl_xor(part, 2, 64);
                part += __shfl_xor(part, 1, 64);
                if (hs == 0) {
                    int grow = b * NN + r0 + rr;
                    int gi   = grow * 4 + f;
                    float y = smY[(r0 + rr) * 4 + f];
                    float knew = scrub(y + bo3[f] + part);    // f(y) = y + p
                    if (s < 3) {
                        astore(kout + gi, knew);
                    } else {
                        float xv = scrub(aload(xc + gi) + (dt * (1.0f / 6.0f)) *
                                   (aload(k1 + gi) + 2.0f * aload(k2 + gi) +
                                    2.0f * aload(k3 + gi) + knew));
                        astore(xn + gi, xv);
                        // out layout (B, N, NSTEP, F): row = b*64+n (host-visible
                        // at kernel end; never read cross-block -> normal store)
                        outp[(size_t)grow * NSTEP * FF + step * FF + f] = xv;
                    }
                }
            }

            ++phase;
            if (phase < 4u * NSTEP) batch_bar(bar, phase * 8u);
        }
        float* t = xc; xc = xn; xn = t;
    }
}

// Pre-swizzle W2 -> fragment-major W2F (verified): chunk (k,ot,kc) is
// 1 KiB; lane l holds B[o = ot*16 + (l&15)][h = kc*32 + (l>>4)*8 + e]
__global__ void swizzle_w2(const float* __restrict__ W2, _Float16* __restrict__ W2F)
{
    int idx = blockIdx.x * 256 + threadIdx.x;       // 0 .. 131071
    int k   = idx >> 16;
    int rem = idx & 65535;
    int ch  = rem >> 9;
    int pos = rem & 511;
    int ot  = ch >> 3, kc = ch & 7;
    int l   = pos >> 3, e = pos & 7;
    int o   = ot * 16 + (l & 15);
    int h   = kc * 32 + (l >> 4) * 8 + e;
    W2F[idx] = (_Float16)W2[(size_t)(k * 256 + h) * 256 + o];
}

// Wo1 [260][256] -> fragment-major f16, K padded to 288 (zeros).
__global__ void swizzle_wo1(const float* __restrict__ Wo1, _Float16* __restrict__ Wo1F)
{
    int idx = blockIdx.x * 256 + threadIdx.x;       // 0 .. 73727
    int ch = idx >> 9, pos = idx & 511;
    int ot = ch / 9, kc = ch - ot * 9;
    int l = pos >> 3, e = pos & 7;
    int k = kc * 32 + (l >> 4) * 8 + e;
    int o = ot * 16 + (l & 15);
    Wo1F[idx] = (k < 260) ? (_Float16)Wo1[(size_t)k * 256 + o] : (_Float16)0.0f;
}

// Wo2 [256][256] -> fragment-major f16.
__global__ void swizzle_wo2(const float* __restrict__ Wo2, _Float16* __restrict__ Wo2F)
{
    int idx = blockIdx.x * 256 + threadIdx.x;       // 0 .. 65535
    int ch = idx >> 9, pos = idx & 511;
    int ot = ch >> 3, kc = ch & 7;
    int l = pos >> 3, e = pos & 7;
    int k = kc * 32 + (l >> 4) * 8 + e;
    int o = ot * 16 + (l & 15);
    Wo2F[idx] = (_Float16)Wo2[(size_t)k * 256 + o];
}

__global__ void init_x(const float* __restrict__ inp, float* __restrict__ x0,
                       unsigned* __restrict__ gcnt)
{
    int i = blockIdx.x * 256 + threadIdx.x;   // i = (b*64+n)*4+f
    if (i < 512) gcnt[i] = 0u;                // reset per-batch barrier counters each replay
    if (i < BB * NN * FF) {
        int f = i & 3, bn = i >> 2;
        x0[i] = scrub(inp[(size_t)(bn * TT) * FF + f]);   // inputs[b][n][0][f]
    }
}

static int find_input(const int* in_sizes, int n_in, int want, unsigned char* used, int dflt) {
    if (dflt >= 0 && dflt < n_in && in_sizes[dflt] == want && !used[dflt]) { used[dflt] = 1; return dflt; }
    for (int i = 0; i < n_in; ++i)
        if (!used[i] && in_sizes[i] == want) { used[i] = 1; return i; }
    return dflt;
}

extern "C" void kernel_launch(void* const* d_in, const int* in_sizes, int n_in,
                              void* d_out, int out_size, void* d_ws, size_t ws_size,
                              hipStream_t stream)
{
    unsigned char used[64] = {0};
    int iInp = find_input(in_sizes, n_in, BB*NN*TT*FF, used, 0);
    int iEdg = find_input(in_sizes, n_in, BB*EE*KK,    used, 1);
    (void)find_input(in_sizes, n_in, EE*NN, used, 2);              // rel_rec (unused)
    (void)find_input(in_sizes, n_in, EE*NN, used, 3);              // rel_send (unused)
    int iW1  = find_input(in_sizes, n_in, KK*8*256,  used, 4);
    int ib1  = find_input(in_sizes, n_in, KK*256,    used, 5);
    int iW2  = find_input(in_sizes, n_in, KK*256*256,used, 6);
    int ib2  = find_input(in_sizes, n_in, KK*256,    used, 7);
    int iWo1 = find_input(in_sizes, n_in, 260*256,   used, 8);
    int ibo1 = find_input(in_sizes, n_in, 256,       used, 9);
    int iWo2 = find_input(in_sizes, n_in, 256*256,   used, 10);
    int ibo2 = find_input(in_sizes, n_in, 256,       used, 11);
    int iWo3 = find_input(in_sizes, n_in, 256*4,     used, 12);
    int ibo3 = find_input(in_sizes, n_in, 4,         used, 13);
    int iTs  = find_input(in_sizes, n_in, TT,        used, 14);
    (void)find_input(in_sizes, n_in, 1, used, 15);                 // pred_steps
    int iSc  = find_input(in_sizes, n_in, 1,         used, 16);    // scale

    const float* inputs = (const float*)d_in[iInp];
    const float* edges  = (const float*)d_in[iEdg];
    const float* W1  = (const float*)d_in[iW1];
    const float* b1  = (const float*)d_in[ib1];
    const float* W2  = (const float*)d_in[iW2];
    const float* b2  = (const float*)d_in[ib2];
    const float* Wo1 = (const float*)d_in[iWo1];
    const float* bo1 = (const float*)d_in[ibo1];
    const float* Wo2 = (const float*)d_in[iWo2];
    const float* bo2 = (const float*)d_in[ibo2];
    const float* Wo3 = (const float*)d_in[iWo3];
    const float* bo3 = (const float*)d_in[ibo3];
    const float* ts  = (const float*)d_in[iTs];
    const void*  scp = d_in[iSc];

    char* ws = (char*)d_ws;
    _Float16* W2F  = (_Float16*)ws;                       // 262144 B
    _Float16* Wo1F = (_Float16*)(ws + 262144);            // 147456 B
    _Float16* Wo2F = (_Float16*)(ws + 409600);            // 131072 B
    float* xA  = (float*)(ws + 540672);
    float* xB  = (float*)(ws + 540672 + 1 * 32768);
    float* k1  = (float*)(ws + 540672 + 2 * 32768);
    float* k2  = (float*)(ws + 540672 + 3 * 32768);
    float* k3  = (float*)(ws + 540672 + 4 * 32768);
    unsigned* gcnt = (unsigned*)(ws + 540672 + 5 * 32768);   // 32 batches x 16 u32

    float* outp = (float*)d_out;   // f32 output

    (void)hipFuncSetAttribute((const void*)ode_kernel,
        hipFuncAttributeMaxDynamicSharedMemorySize, SMEM2);

    swizzle_w2<<<dim3(512), dim3(256), 0, stream>>>(W2, W2F);
    swizzle_wo1<<<dim3(288), dim3(256), 0, stream>>>(Wo1, Wo1F);
    swizzle_wo2<<<dim3(256), dim3(256), 0, stream>>>(Wo2, Wo2F);
    init_x<<<dim3(32), dim3(256), 0, stream>>>(inputs, xA, gcnt);

    ode_kernel<<<dim3(256), dim3(512), SMEM2, stream>>>(
        edges, W1, b1, W2F, b2, Wo1F, bo1, Wo2F, bo2, Wo3, bo3,
        ts, scp, xA, xB, k1, k2, k3, outp, gcnt);
}

// Round 13
// 1509.079 us; speedup vs baseline: 5.3695x; 4.9123x over previous
//
#include <hip/hip_runtime.h>

// Problem constants (fixed by setup_inputs)
#define BB 32
#define NN 64
#define TT 11
#define FF 4
#define KK 2
#define EE 4032      // N*(N-1)
#define NSTEP 10

typedef _Float16 f16x8 __attribute__((ext_vector_type(8)));
typedef float    f32x4v __attribute__((ext_vector_type(4)));

// ---- fused kernel LDS (512 thr, 8 receivers, grid 256 = 1 block/CU) ----
// phase C: u dbuf [2][64][512B XOR-swz] 64K | B-tile dbuf [2][32K] 64K |
//          vbh dbuf [2][8][256]f16 8K | y [64][4]f32 1K | wgt [2][8][64]f32 4K
// phase D aliases the (dead) u region: augH [16][296]f16 9472 | P1H [16][264]f16 8448 |
//          P2 [16][256]f32 16384  (total 34304 < 65536)
#define OFF_U0   0
#define OFF_B    65536
#define OFF_VB   131072
#define OFF_Y    139264
#define OFF_WGT  140288
#define SMEM2    144384
#define OFF_AUGH 0
#define OFF_P1H  9472
#define OFF_P2   17920

__device__ __forceinline__ float scrub(float v) {
    return fminf(fmaxf(v, -3.0e4f), 3.0e4f);   // inactive when correct (|x| <~ 600)
}

__device__ __forceinline__ float load_dt(const float* ts, const void* scp, int step) {
    float t0 = ts[step], t1 = ts[step + 1];
    int w = ((const int*)scp)[0];
    float scl;
    if (w > 0 && w < 1000000) scl = (float)w;            // int32 (live path)
    else {
        float f = __int_as_float(w);
        scl = (f > 0.5f && f < 1.0e6f) ? f : 10.0f;
    }
    return (t1 - t0) / scl;
}

typedef __attribute__((address_space(1))) const unsigned int glb_u32;
typedef __attribute__((address_space(3))) unsigned int lds_u32;
__device__ __forceinline__ void gload_lds16(const void* g, void* l) {
    __builtin_amdgcn_global_load_lds((glb_u32*)g, (lds_u32*)l, 16, 0, 0);
}

// Stage one 32KB B tile (k,ch2,h): 32 chunks of 1KB laid ni-major/kc'-minor.
// LDS dest is wave-uniform base (+ HW lane*16); global source is per-lane (srcOff).
// DMA drains at the next __syncthreads (compiler emits vmcnt(0) before s_barrier).
__device__ __forceinline__ void stage_B(char* smem, int bufsel, int k, int ch2, int h,
    const _Float16* __restrict__ W2F, int wn, const int* srcOff)
{
    const char* base = (const char*)W2F
        + ((size_t)((k * 16 + ch2 * 8) * 8 + h * 4)) * 1024;
    char* dst = smem + OFF_B + bufsel * 32768 + wn * 1024;
    #pragma unroll
    for (int r = 0; r < 4; ++r)
        gload_lds16(base + srcOff[r], dst + r * 8192);
}

// u-build (512 thr): u[s][h] = sum_f y_s[f] * W1send[k][f][h], f16, XOR-swizzled rows.
__device__ __forceinline__ void build_uk(char* smem, int buf, int k, int tid,
    const float* __restrict__ W1g, const float* smY)
{
    int hg = tid & 31, sb = tid >> 5;          // sb = 0..15
    const float* w1p = W1g + k * 2048 + hg * 8;
    f32x4v wA[4], wB[4];
    #pragma unroll
    for (int f = 0; f < 4; ++f) {
        wA[f] = *(const f32x4v*)(w1p + f * 256);
        wB[f] = *(const f32x4v*)(w1p + f * 256 + 4);
    }
    const int swz = (hg * 16) ^ ((sb & 7) << 4);   // s&7 == sb&7 (it*16 ≡ 0 mod 8)
    char* ub = smem + OFF_U0 + buf * 32768;
    #pragma unroll
    for (int it = 0; it < 4; ++it) {
        int s = sb + it * 16;
        f32x4v yv = *(const f32x4v*)(smY + s * 4);
        f16x8 uv;
        #pragma unroll
        for (int e = 0; e < 4; ++e) {
            float vA = yv[0]*wA[0][e] + yv[1]*wA[1][e] + yv[2]*wA[2][e] + yv[3]*wA[3][e];
            float vB = yv[0]*wB[0][e] + yv[1]*wB[1][e] + yv[2]*wB[2][e] + yv[3]*wB[3][e];
            uv[e]     = (_Float16)vA;
            uv[e + 4] = (_Float16)vB;
        }
        *(f16x8*)(ub + s * 512 + swz) = uv;
    }
}

// vbh[buf][rv][h] = f16( b1 + sum_f y_recv[f] * W1recv[k][f][h] ), rv = 0..7
__device__ __forceinline__ void build_vbh(_Float16* smVBH, int buf, int k, int tid, int r0,
    const float* __restrict__ W1g, const float* __restrict__ b1g, const float* smY)
{
    #pragma unroll
    for (int it = 0; it < 4; ++it) {
        int i = tid + it * 512;
        int rv = i >> 8, h = i & 255;
        float acch = b1g[k * 256 + h];
        #pragma unroll
        for (int f = 0; f < 4; ++f)
            acch += smY[(r0 + rv) * 4 + f] * W1g[k * 2048 + (4 + f) * 256 + h];
        smVBH[buf * 2048 + i] = (_Float16)acch;
    }
}

__device__ __forceinline__ void acc_init(const float* __restrict__ b2g, int k, int ch2,
                                         int ln15, f32x4v acc[4][8])
{
    #pragma unroll
    for (int ni = 0; ni < 8; ++ni) {
        float bv = b2g[k * 256 + ch2 * 128 + ni * 16 + ln15];
        #pragma unroll
        for (int mi = 0; mi < 4; ++mi)
            acc[mi][ni] = (f32x4v){bv, bv, bv, bv};
    }
}

// 4-kc GEMM sub-pass: reads u[ubuf]/vb[vbuf] + B tile [Bbuf] (all LDS), 128 MFMA/wave.
__device__ __forceinline__ void gemm4(char* smem, int ubuf, int vbuf, int Bbuf, int rv,
    int kcBase, int lane, int ln15, int lg, const int* uoff, int xm6,
    f32x4v acc[4][8])
{
    const char* ubase = smem + OFF_U0 + ubuf * 32768;
    const _Float16* vbase = (const _Float16*)(smem + OFF_VB) + vbuf * 2048 + rv * 256;
    const char* Bbase = smem + OFF_B + Bbuf * 32768;
    #pragma unroll
    for (int kc2 = 0; kc2 < 4; ++kc2) {
        const int kc = kcBase + kc2;
        f16x8 bfr[8];
        #pragma unroll
        for (int ni = 0; ni < 8; ++ni)
            bfr[ni] = *(const f16x8*)(Bbase + (ni * 4 + kc2) * 1024 + lane * 16);
        f16x8 vbv = *(const f16x8*)(vbase + kc * 32 + lg * 8);
        const int kco = (kc * 64) ^ xm6;
        f16x8 af[4];
        f16x8 z = {};
        #pragma unroll
        for (int mi = 0; mi < 4; ++mi) {
            f16x8 uv = *(const f16x8*)(ubase + uoff[mi] + kco);
            af[mi] = __builtin_elementwise_max(uv + vbv, z);
        }
        __builtin_amdgcn_s_setprio(1);
        #pragma unroll
        for (int mi = 0; mi < 4; ++mi)
            #pragma unroll
            for (int ni = 0; ni < 8; ++ni)
                acc[mi][ni] = __builtin_amdgcn_mfma_f32_16x16x32_f16(
                    af[mi], bfr[ni], acc[mi][ni], 0, 0, 0);
        __builtin_amdgcn_s_setprio(0);
    }
}

// epilogue per (k, col-half): relu * edge_w into rsum regs.
__device__ __forceinline__ void epi(const float* smWgt, int k, int rv, int lg,
    const f32x4v acc[4][8], float rsum[8])
{
    #pragma unroll
    for (int mi = 0; mi < 4; ++mi)
        #pragma unroll
        for (int rr = 0; rr < 4; ++rr) {
            // C/D: col = lane&15, row = lg*4 + rr  [m89/m91]; sender s = mi*16 + row
            float w = smWgt[k * 512 + rv * 64 + mi * 16 + lg * 4 + rr];
            #pragma unroll
            for (int ni = 0; ni < 8; ++ni)
                rsum[ni] += fmaxf(acc[mi][ni][rr], 0.0f) * w;
        }
}

// Fused per-stage kernel (v13 = v9 revert + LDS-staged W2F B-tiles):
// the bfr B-operand now streams L2 -> LDS via global_load_lds DMA (double-buffered
// 32KB tiles, issued right after each barrier, consumed one barrier later) and is
// read as conflict-free contiguous ds_read_b128. Kills the exposed L2 latency +
// 8x redundant per-wave W2F streams that starved MFMA issue (MfmaUtil 30%).
__global__ __launch_bounds__(512, 2)
void stage_kernel(int stage, int step,
    const float* __restrict__ edges, const float* __restrict__ W1g,
    const float* __restrict__ b1g,   const _Float16* __restrict__ W2F,
    const float* __restrict__ b2g,
    const _Float16* __restrict__ Wo1F, const float* __restrict__ bo1,
    const _Float16* __restrict__ Wo2F, const float* __restrict__ bo2,
    const float* __restrict__ Wo3, const float* __restrict__ bo3,
    const float* __restrict__ ts,  const void* __restrict__ scp,
    const float* __restrict__ xcur, const float* __restrict__ kprev,
    float* __restrict__ kout,
    const float* __restrict__ k1b, const float* __restrict__ k2b,
    const float* __restrict__ k3b,
    float* __restrict__ xnext, float* __restrict__ outp)
{
    extern __shared__ char smem[];
    _Float16* smVBH = (_Float16*)(smem + OFF_VB);
    float*  smY   = (float*)(smem + OFF_Y);
    float*  smWgt = (float*)(smem + OFF_WGT);

    const int tid = threadIdx.x;
    const int b   = blockIdx.x >> 3;
    const int rg  = blockIdx.x & 7;
    const int r0  = rg * 8;

    const float dt = load_dt(ts, scp, step);
    const float cc = (stage == 0) ? 0.0f : ((stage == 3) ? 1.0f : 0.5f);

    // ---- P0: y (all 64 nodes), edge weights (sender-major) ----
    if (tid < 256) {
        int gi = (b * NN) * FF + tid;           // tid = n*4+f
        float y = xcur[gi];
        if (stage != 0) y += cc * dt * kprev[gi];
        smY[tid] = scrub(y);
    }
    #pragma unroll
    for (int it = 0; it < 2; ++it) {
        // smWgt[k][rv][s] ; diagonal s==r -> 0
        int i = tid + it * 512;
        int k = i >> 9, m = i & 511;
        int rv2 = m >> 6, s = m & 63;
        int r = r0 + rv2;
        float w = 0.0f;
        if (s != r) {
            int j = s - (s > r ? 1 : 0);
            w = edges[((size_t)b * EE + r * 63 + j) * KK + k];
        }
        smWgt[i] = w;
    }

    const int lane = tid & 63;
    const int wn   = tid >> 6;    // 8 waves: wave wn owns receiver rv = wn
    const int rv   = wn;
    const int ln15 = lane & 15;
    const int lg   = lane >> 4;   // 0..3

    // swizzled u read offsets: byte = s*512 + ((kc*64 + lg*16) ^ ((s&7)<<4)),
    // s = mi*16 + ln15 -> s&7 = ln15&7 (per-lane constant).
    const int xm45 = (ln15 & 3) << 4;
    const int xm6  = (ln15 & 4) << 4;
    int uoff[4];
    #pragma unroll
    for (int mi = 0; mi < 4; ++mi) {
        int s = mi * 16 + ln15;
        uoff[mi] = s * 512 + ((lg * 16) ^ xm45);
    }
    // per-thread B-tile DMA source offsets (tile-internal, tile-base-independent):
    // unit u = r*512+tid -> chunk c=u>>6 (ni=c>>2, kc'=c&3), word w=u&63.
    int srcOff[4];
    #pragma unroll
    for (int r = 0; r < 4; ++r) {
        int u = r * 512 + tid;
        int c = u >> 6, w = u & 63;
        srcOff[r] = ((c >> 2) * 8 + (c & 3)) * 1024 + w * 16;
    }

    float rsA[8], rsB[8];         // col-half 0 / 1, accumulated across k
    #pragma unroll
    for (int ni = 0; ni < 8; ++ni) { rsA[ni] = 0.0f; rsB[ni] = 0.0f; }
    f32x4v acc[4][8];

    __syncthreads();              // S0: smY/smWgt ready

    // ---- build k=0 + first B tile ----
    build_uk(smem, 0, 0, tid, W1g, smY);
    build_vbh(smVBH, 0, 0, tid, r0, W1g, b1g, smY);
    stage_B(smem, 0, 0, 0, 0, W2F, wn, srcOff);     // T1 (k0,ch0,h0) -> B0
    __syncthreads();              // S1: u0/vb0/B0 ready

    stage_B(smem, 1, 0, 0, 1, W2F, wn, srcOff);     // T2 -> B1
    build_uk(smem, 1, 1, tid, W1g, smY);            // k=1 build overlaps gemm
    build_vbh(smVBH, 1, 1, tid, r0, W1g, b1g, smY);
    acc_init(b2g, 0, 0, ln15, acc);
    gemm4(smem, 0, 0, 0, rv, 0, lane, ln15, lg, uoff, xm6, acc);
    __syncthreads();              // S2: B1 ready, B0 free, u1/vb1 ready

    stage_B(smem, 0, 0, 1, 0, W2F, wn, srcOff);     // T3 (k0,ch1,h0) -> B0
    gemm4(smem, 0, 0, 1, rv, 4, lane, ln15, lg, uoff, xm6, acc);
    epi(smWgt, 0, rv, lg, acc, rsA);
    __syncthreads();              // S3

    stage_B(smem, 1, 0, 1, 1, W2F, wn, srcOff);     // T4 -> B1
    acc_init(b2g, 0, 1, ln15, acc);
    gemm4(smem, 0, 0, 0, rv, 0, lane, ln15, lg, uoff, xm6, acc);
    __syncthreads();              // S4

    stage_B(smem, 0, 1, 0, 0, W2F, wn, srcOff);     // T5 (k1,ch0,h0) -> B0
    gemm4(smem, 0, 0, 1, rv, 4, lane, ln15, lg, uoff, xm6, acc);
    epi(smWgt, 0, rv, lg, acc, rsB);
    __syncthreads();              // S5

    stage_B(smem, 1, 1, 0, 1, W2F, wn, srcOff);     // T6 -> B1
    acc_init(b2g, 1, 0, ln15, acc);
    gemm4(smem, 1, 1, 0, rv, 0, lane, ln15, lg, uoff, xm6, acc);
    __syncthreads();              // S6

    stage_B(smem, 0, 1, 1, 0, W2F, wn, srcOff);     // T7 (k1,ch1,h0) -> B0
    gemm4(smem, 1, 1, 1, rv, 4, lane, ln15, lg, uoff, xm6, acc);
    epi(smWgt, 1, rv, lg, acc, rsA);
    __syncthreads();              // S7

    stage_B(smem, 1, 1, 1, 1, W2F, wn, srcOff);     // T8 -> B1
    acc_init(b2g, 1, 1, ln15, acc);
    gemm4(smem, 1, 1, 0, rv, 0, lane, ln15, lg, uoff, xm6, acc);
    __syncthreads();              // S8

    gemm4(smem, 1, 1, 1, rv, 4, lane, ln15, lg, uoff, xm6, acc);
    epi(smWgt, 1, rv, lg, acc, rsB);

    // ---- reduce over lg (senders) + write agg row directly as f16 A-tile ----
    #pragma unroll
    for (int ni = 0; ni < 8; ++ni) {
        rsA[ni] += __shfl_xor(rsA[ni], 16, 64);
        rsA[ni] += __shfl_xor(rsA[ni], 32, 64);
        rsB[ni] += __shfl_xor(rsB[ni], 16, 64);
        rsB[ni] += __shfl_xor(rsB[ni], 32, 64);
    }
    // augH aliases u0 (dead since S6: no u0 reads after S5). rows 8..15 / cols
    // 260..287 stay finite garbage — zero-padded Wo1F kills cols >=260; rows >=8
    // never read back (MFMA rows independent).
    _Float16* smAugH = (_Float16*)(smem + OFF_AUGH);  // [16][296]
    if (lane < 16) {
        #pragma unroll
        for (int ni = 0; ni < 8; ++ni) {
            smAugH[rv * 296 + 4   + ni * 16 + ln15] = (_Float16)rsA[ni];
            smAugH[rv * 296 + 132 + ni * 16 + ln15] = (_Float16)rsB[ni];
        }
    } else if (lg == 1 && ln15 < 4) {
        smAugH[rv * 296 + ln15] = (_Float16)smY[(r0 + rv) * 4 + ln15];
    }
    __syncthreads();              // augH ready

    // ======== phase D: node MLP via f16 MFMA (rows r0..r0+7) ========
    _Float16* smP1H = (_Float16*)(smem + OFF_P1H);   // [16][264] (256 used)
    float*    smP2  = (float*)(smem + OFF_P2);       // [16][256]

    const int ot0 = wn * 2, ot1 = ot0 + 1;   // each wave owns two 16-col tiles

    // ---- L1: aug16 @ Wo1F (K=288, 9 k-tiles) + bo1, relu -> P1H f16 ----
    {
        float b0 = bo1[ot0 * 16 + ln15], b1v = bo1[ot1 * 16 + ln15];
        f32x4v a0 = {b0, b0, b0, b0}, a1 = {b1v, b1v, b1v, b1v};
        const _Float16* bb0 = Wo1F + (size_t)(ot0 * 9) * 512 + lane * 8;
        const _Float16* bb1 = Wo1F + (size_t)(ot1 * 9) * 512 + lane * 8;
        #pragma unroll
        for (int kc = 0; kc < 9; ++kc) {
            f16x8 av  = *(const f16x8*)(smAugH + ln15 * 296 + kc * 32 + lg * 8);
            f16x8 bf0 = *(const f16x8*)(bb0 + kc * 512);
            f16x8 bf1 = *(const f16x8*)(bb1 + kc * 512);
            a0 = __builtin_amdgcn_mfma_f32_16x16x32_f16(av, bf0, a0, 0, 0, 0);
            a1 = __builtin_amdgcn_mfma_f32_16x16x32_f16(av, bf1, a1, 0, 0, 0);
        }
        // P1H disjoint from augH -> no barrier needed before these writes
        #pragma unroll
        for (int rr = 0; rr < 4; ++rr) {
            int row = lg * 4 + rr;            // C/D: col = lane&15, row = lg*4+rr
            smP1H[row * 264 + ot0 * 16 + ln15] = (_Float16)fmaxf(a0[rr], 0.0f);
            smP1H[row * 264 + ot1 * 16 + ln15] = (_Float16)fmaxf(a1[rr], 0.0f);
        }
    }
    __syncthreads();
    // ---- L2: P1 @ Wo2F (K=256, 8 k-tiles) + bo2, relu -> P2 f32 ----
    {
        float b0 = bo2[ot0 * 16 + ln15], b1v = bo2[ot1 * 16 + ln15];
        f32x4v a0 = {b0, b0, b0, b0}, a1 = {b1v, b1v, b1v, b1v};
        const _Float16* bb0 = Wo2F + (size_t)(ot0 * 8) * 512 + lane * 8;
        const _Float16* bb1 = Wo2F + (size_t)(ot1 * 8) * 512 + lane * 8;
        #pragma unroll
        for (int kc = 0; kc < 8; ++kc) {
            f16x8 av  = *(const f16x8*)(smP1H + ln15 * 264 + kc * 32 + lg * 8);
            f16x8 bf0 = *(const f16x8*)(bb0 + kc * 512);
            f16x8 bf1 = *(const f16x8*)(bb1 + kc * 512);
            a0 = __builtin_amdgcn_mfma_f32_16x16x32_f16(av, bf0, a0, 0, 0, 0);
            a1 = __builtin_amdgcn_mfma_f32_16x16x32_f16(av, bf1, a1, 0, 0, 0);
        }
        #pragma unroll
        for (int rr = 0; rr < 4; ++rr) {
            int row = lg * 4 + rr;
            smP2[row * 256 + ot0 * 16 + ln15] = fmaxf(a0[rr], 0.0f);
            smP2[row * 256 + ot1 * 16 + ln15] = fmaxf(a1[rr], 0.0f);
        }
    }
    __syncthreads();
    // ---- L3 (256 -> 4) + residual + RK4 tail ----
    {
        int rr = tid >> 6, f = (tid >> 4) & 3, hs = tid & 15;   // one wave per row, 8 rows
        float part = 0.0f;
        #pragma unroll
        for (int j = 0; j < 16; ++j) {
            int h = hs + j * 16;
            part += smP2[rr * 256 + h] * Wo3[h * 4 + f];
        }
        part += __shfl_xor(part, 8, 64);
        part += __shfl_xor(part, 4, 64);
        part += __shfl_xor(part, 2, 64);
        part += __shfl_xor(part, 1, 64);
        if (hs == 0) {
            int grow = b * NN + r0 + rr;
            int gi   = grow * 4 + f;
            float y = smY[(r0 + rr) * 4 + f];
            float knew = scrub(y + bo3[f] + part);    // f(y) = y + p
            if (stage < 3) {
                kout[gi] = knew;
            } else {
                float xn = scrub(xcur[gi] + (dt * (1.0f / 6.0f)) *
                           (k1b[gi] + 2.0f * k2b[gi] + 2.0f * k3b[gi] + knew));
                xnext[gi] = xn;
                // out layout (B, N, NSTEP, F): row = b*64+n
                outp[(size_t)grow * NSTEP * FF + step * FF + f] = xn;
            }
        }
    }
}

// Pre-swizzle W2 -> fragment-major W2F (verified): chunk (k,ot,kc) is
// 1 KiB; lane l holds B[o = ot*16 + (l&15)][h = kc*32 + (l>>4)*8 + e]
__global__ void swizzle_w2(const float* __restrict__ W2, _Float16* __restrict__ W2F)
{
    int idx = blockIdx.x * 256 + threadIdx.x;       // 0 .. 131071
    int k   = idx >> 16;
    int rem = idx & 65535;
    int ch  = rem >> 9;
    int pos = rem & 511;
    int ot  = ch >> 3, kc = ch & 7;
    int l   = pos >> 3, e = pos & 7;
    int o   = ot * 16 + (l & 15);
    int h   = kc * 32 + (l >> 4) * 8 + e;
    W2F[idx] = (_Float16)W2[(size_t)(k * 256 + h) * 256 + o];
}

// Wo1 [260][256] -> fragment-major f16, K padded to 288 (zeros).
__global__ void swizzle_wo1(const float* __restrict__ Wo1, _Float16* __restrict__ Wo1F)
{
    int idx = blockIdx.x * 256 + threadIdx.x;       // 0 .. 73727
    int ch = idx >> 9, pos = idx & 511;
    int ot = ch / 9, kc = ch - ot * 9;
    int l = pos >> 3, e = pos & 7;
    int k = kc * 32 + (l >> 4) * 8 + e;
    int o = ot * 16 + (l & 15);
    Wo1F[idx] = (k < 260) ? (_Float16)Wo1[(size_t)k * 256 + o] : (_Float16)0.0f;
}

// Wo2 [256][256] -> fragment-major f16.
__global__ void swizzle_wo2(const float* __restrict__ Wo2, _Float16* __restrict__ Wo2F)
{
    int idx = blockIdx.x * 256 + threadIdx.x;       // 0 .. 65535
    int ch = idx >> 9, pos = idx & 511;
    int ot = ch >> 3, kc = ch & 7;
    int l = pos >> 3, e = pos & 7;
    int k = kc * 32 + (l >> 4) * 8 + e;
    int o = ot * 16 + (l & 15);
    Wo2F[idx] = (_Float16)Wo2[(size_t)k * 256 + o];
}

__global__ void init_x(const float* __restrict__ inp, float* __restrict__ x0)
{
    int i = blockIdx.x * 256 + threadIdx.x;   // i = (b*64+n)*4+f
    if (i < BB * NN * FF) {
        int f = i & 3, bn = i >> 2;
        x0[i] = scrub(inp[(size_t)(bn * TT) * FF + f]);   // inputs[b][n][0][f]
    }
}

static int find_input(const int* in_sizes, int n_in, int want, unsigned char* used, int dflt) {
    if (dflt >= 0 && dflt < n_in && in_sizes[dflt] == want && !used[dflt]) { used[dflt] = 1; return dflt; }
    for (int i = 0; i < n_in; ++i)
        if (!used[i] && in_sizes[i] == want) { used[i] = 1; return i; }
    return dflt;
}

extern "C" void kernel_launch(void* const* d_in, const int* in_sizes, int n_in,
                              void* d_out, int out_size, void* d_ws, size_t ws_size,
                              hipStream_t stream)
{
    unsigned char used[64] = {0};
    int iInp = find_input(in_sizes, n_in, BB*NN*TT*FF, used, 0);
    int iEdg = find_input(in_sizes, n_in, BB*EE*KK,    used, 1);
    (void)find_input(in_sizes, n_in, EE*NN, used, 2);              // rel_rec (unused)
    (void)find_input(in_sizes, n_in, EE*NN, used, 3);              // rel_send (unused)
    int iW1  = find_input(in_sizes, n_in, KK*8*256,  used, 4);
    int ib1  = find_input(in_sizes, n_in, KK*256,    used, 5);
    int iW2  = find_input(in_sizes, n_in, KK*256*256,used, 6);
    int ib2  = find_input(in_sizes, n_in, KK*256,    used, 7);
    int iWo1 = find_input(in_sizes, n_in, 260*256,   used, 8);
    int ibo1 = find_input(in_sizes, n_in, 256,       used, 9);
    int iWo2 = find_input(in_sizes, n_in, 256*256,   used, 10);
    int ibo2 = find_input(in_sizes, n_in, 256,       used, 11);
    int iWo3 = find_input(in_sizes, n_in, 256*4,     used, 12);
    int ibo3 = find_input(in_sizes, n_in, 4,         used, 13);
    int iTs  = find_input(in_sizes, n_in, TT,        used, 14);
    (void)find_input(in_sizes, n_in, 1, used, 15);                 // pred_steps
    int iSc  = find_input(in_sizes, n_in, 1,         used, 16);    // scale

    const float* inputs = (const float*)d_in[iInp];
    const float* edges  = (const float*)d_in[iEdg];
    const float* W1  = (const float*)d_in[iW1];
    const float* b1  = (const float*)d_in[ib1];
    const float* W2  = (const float*)d_in[iW2];
    const float* b2  = (const float*)d_in[ib2];
    const float* Wo1 = (const float*)d_in[iWo1];
    const float* bo1 = (const float*)d_in[ibo1];
    const float* Wo2 = (const float*)d_in[iWo2];
    const float* bo2 = (const float*)d_in[ibo2];
    const float* Wo3 = (const float*)d_in[iWo3];
    const float* bo3 = (const float*)d_in[ibo3];
    const float* ts  = (const float*)d_in[iTs];
    const void*  scp = d_in[iSc];

    char* ws = (char*)d_ws;
    _Float16* W2F  = (_Float16*)ws;                       // 262144 B
    _Float16* Wo1F = (_Float16*)(ws + 262144);            // 147456 B
    _Float16* Wo2F = (_Float16*)(ws + 409600);            // 131072 B
    float* xA  = (float*)(ws + 540672);
    float* xB  = (float*)(ws + 540672 + 1 * 32768);
    float* k1  = (float*)(ws + 540672 + 2 * 32768);
    float* k2  = (float*)(ws + 540672 + 3 * 32768);
    float* k3  = (float*)(ws + 540672 + 4 * 32768);

    float* outp = (float*)d_out;   // f32 output

    (void)hipFuncSetAttribute((const void*)stage_kernel,
        hipFuncAttributeMaxDynamicSharedMemorySize, SMEM2);

    swizzle_w2<<<dim3(512), dim3(256), 0, stream>>>(W2, W2F);
    swizzle_wo1<<<dim3(288), dim3(256), 0, stream>>>(Wo1, Wo1F);
    swizzle_wo2<<<dim3(256), dim3(256), 0, stream>>>(Wo2, Wo2F);
    init_x<<<dim3(32), dim3(256), 0, stream>>>(inputs, xA);

    float* xc = xA;
    float* xn = xB;
    for (int step = 0; step < NSTEP; ++step) {
        float* kprevs[4] = { xc, k1, k2, k3 };   // kprev per stage (xc unused at s0)
        float* kouts[4]  = { k1, k2, k3, k3 };   // kout per stage (s3 -> tail path)
        for (int s = 0; s < 4; ++s) {
            stage_kernel<<<dim3(256), dim3(512), SMEM2, stream>>>(s, step,
                edges, W1, b1, W2F, b2,
                Wo1F, bo1, Wo2F, bo2, Wo3, bo3, ts, scp, xc, kprevs[s],
                kouts[s], k1, k2, k3, xn, outp);
        }
        float* t = xc; xc = xn; xn = t;
    }
}